// Round 7
// baseline (106.122 us; speedup 1.0000x reference)
//
#include <hip/hip_runtime.h>
#include <math.h>

#define B 512
#define T 256
#define N 200
#define H 64
#define TN (T*N)     // 51200

#define ARS 232              // A row stride in bf16 (464 B; 29 slots, odd -> skewed)
#define ASAMP (N*ARS)        // 46400 bf16 per sample = 92800 B

#define XTRS 80              // Xt row stride bytes: 32 bf16 = 64 B data + 16 pad (5 slots, odd)

// k_corr LDS map (bytes):
//  [0,     25600)  S0: chunk staging [32 t][200 n] f32
//  [25600, 51200)  S1: chunk staging (double buffer)
//  [51200, 67200)  Xt0: [200 n][32 t] bf16, row stride 80 B
//  [67200, 83200)  Xt1: (double buffer)
//  [83200, 86400)  musum [4][200] f32
//  [86400, 87200)  varA[200] f32 (raw sum-of-squares diag)
//  [87200, 88000)  muA[200] f32
//  [88000, 88800)  rsA[200] f32
//  image: [0, 48256) aliases S0/S1 after the K-loop (two 96/104-row halves)
#define KC_S0    0
#define KC_S1    25600
#define KC_XT0   51200
#define KC_XT1   67200
#define KC_MUS   83200
#define KC_VARA  86400
#define KC_MUA   87200
#define KC_RSA   88000
#define KC_SZ    88800

typedef short short8 __attribute__((ext_vector_type(8)));
typedef float f32x4 __attribute__((ext_vector_type(4)));
typedef float f32x16 __attribute__((ext_vector_type(16)));

__device__ __forceinline__ unsigned bf16r(float x) {
    unsigned u = __float_as_uint(x);
    return (u + 0x7fffu + ((u >> 16) & 1u)) >> 16;   // round-to-nearest-even
}
__device__ __forceinline__ float bf2f(unsigned short u) {
    return __uint_as_float(((unsigned)u) << 16);
}

__device__ __forceinline__ void gll16(const void* g, void* l) {
    __builtin_amdgcn_global_load_lds(
        (const __attribute__((address_space(1))) unsigned*)g,
        (__attribute__((address_space(3))) unsigned*)l, 16, 0, 0);
}

// ================= K1: per-sample |corr| -> bf16 A[200][232] + dinv =================
__global__ __launch_bounds__(512) void k_corr(const float* __restrict__ data,
                                              unsigned short* __restrict__ Abf,
                                              float* __restrict__ dinv) {
    __shared__ __align__(16) unsigned char LDS[KC_SZ];
    const int tid  = threadIdx.x;
    const int b    = blockIdx.x;
    const int lane = tid & 63;
    const int wid  = tid >> 6;
    const int l31  = lane & 31;
    const int hi   = lane >> 5;
    const float4* db4 = (const float4*)(data + (size_t)b * TN);

    f32x16 acc[7] = {};
    float mu0 = 0.f, mu1 = 0.f;
    const int n0 = tid % 200, q0 = tid / 200;            // transpose unit 0 (all threads)
    const int n1 = (tid + 512) % 200, q1 = (tid + 512) / 200;  // unit 1 (tid<288)

    int arow = wid * 32 + l31; if (arow > 199) arow = 199;
    int bcc[7];
#pragma unroll
    for (int ct = 0; ct < 7; ++ct) { int c2 = ct * 32 + l31; bcc[ct] = (c2 > 199) ? 199 : c2; }

    // ---- prologue: stage chunk 0 ----
    {
        const float4* src = db4;
#pragma unroll
        for (int i = 0; i < 3; ++i) {
            int idx = tid + i * 512;
            gll16(src + idx, LDS + KC_S0 + idx * 16);
        }
        if (tid < 64) { int idx = tid + 1536; gll16(src + idx, LDS + KC_S0 + idx * 16); }
    }
    __syncthreads();

    // ---- pipelined K-loop: stage(c+1) || transpose(c) || MFMA(c-1), 1 barrier/chunk ----
    for (int c = 0; c < 8; ++c) {
        // issue next chunk's loads (async, drained by this iteration's end barrier)
        if (c < 7) {
            unsigned char* Snext = LDS + (((c + 1) & 1) ? KC_S1 : KC_S0);
            const float4* src = db4 + (c + 1) * 1600;
#pragma unroll
            for (int i = 0; i < 3; ++i) {
                int idx = tid + i * 512;
                gll16(src + idx, Snext + idx * 16);
            }
            if (tid < 64) { int idx = tid + 1536; gll16(src + idx, Snext + idx * 16); }
        }
        // transpose chunk c: S[c&1] f32 [32t][200n] -> Xt[c&1] bf16 [200n][32t]
        {
            const float* Sc = (const float*)(LDS + ((c & 1) ? KC_S1 : KC_S0));
            unsigned char* Xc = LDS + ((c & 1) ? KC_XT1 : KC_XT0);
            {   // unit 0
                const float* s0 = Sc + (q0 * 8) * 200 + n0;
                unsigned u[4]; float a = 0.f;
#pragma unroll
                for (int j = 0; j < 4; ++j) {
                    unsigned b0 = bf16r(s0[(2 * j) * 200]);
                    unsigned b1 = bf16r(s0[(2 * j + 1) * 200]);
                    a += bf2f((unsigned short)b0) + bf2f((unsigned short)b1);
                    u[j] = b0 | (b1 << 16);
                }
                mu0 += a;
                uint4 pk; pk.x = u[0]; pk.y = u[1]; pk.z = u[2]; pk.w = u[3];
                *(uint4*)(Xc + n0 * XTRS + q0 * 16) = pk;
            }
            if (tid < 288) {   // unit 1
                const float* s0 = Sc + (q1 * 8) * 200 + n1;
                unsigned u[4]; float a = 0.f;
#pragma unroll
                for (int j = 0; j < 4; ++j) {
                    unsigned b0 = bf16r(s0[(2 * j) * 200]);
                    unsigned b1 = bf16r(s0[(2 * j + 1) * 200]);
                    a += bf2f((unsigned short)b0) + bf2f((unsigned short)b1);
                    u[j] = b0 | (b1 << 16);
                }
                mu1 += a;
                uint4 pk; pk.x = u[0]; pk.y = u[1]; pk.z = u[2]; pk.w = u[3];
                *(uint4*)(Xc + n1 * XTRS + q1 * 16) = pk;
            }
        }
        // MFMA on previous chunk (Xt[(c-1)&1], published by last barrier)
        if (c > 0 && wid < 7) {
            const unsigned char* Xp = LDS + (((c - 1) & 1) ? KC_XT1 : KC_XT0);
#pragma unroll
            for (int kc = 0; kc < 2; ++kc) {
                short8 a = *(const short8*)(Xp + arow * XTRS + kc * 32 + hi * 16);
#pragma unroll
                for (int ct = 0; ct < 7; ++ct) {
                    short8 bb = *(const short8*)(Xp + bcc[ct] * XTRS + kc * 32 + hi * 16);
                    acc[ct] = __builtin_amdgcn_mfma_f32_32x32x16_bf16(a, bb, acc[ct], 0, 0, 0);
                }
            }
        }
        __syncthreads();   // publishes Xt[c&1]; drains stage(c+1)
    }
    // ---- final MFMA chunk 7 (Xt1) ----
    if (wid < 7) {
        const unsigned char* Xp = LDS + KC_XT1;
#pragma unroll
        for (int kc = 0; kc < 2; ++kc) {
            short8 a = *(const short8*)(Xp + arow * XTRS + kc * 32 + hi * 16);
#pragma unroll
            for (int ct = 0; ct < 7; ++ct) {
                short8 bb = *(const short8*)(Xp + bcc[ct] * XTRS + kc * 32 + hi * 16);
                acc[ct] = __builtin_amdgcn_mfma_f32_32x32x16_bf16(a, bb, acc[ct], 0, 0, 0);
            }
        }
    }

    // ---- mu partials + raw diag (compile-time acc indices only) ----
    *(float*)(LDS + KC_MUS + (q0 * 200 + n0) * 4) = mu0;
    if (tid < 288) *(float*)(LDS + KC_MUS + (q1 * 200 + n1) * 4) = mu1;
#pragma unroll
    for (int ct = 0; ct < 7; ++ct) {
        if (wid == ct) {
#pragma unroll
            for (int r = 0; r < 16; ++r) {
                int rowin = (r & 3) + 8 * (r >> 2) + 4 * hi;   // row within panel
                int n = ct * 32 + rowin;
                if (l31 == rowin && n < 200)
                    *(float*)(LDS + KC_VARA + n * 4) = acc[ct][r];   // S_nn
            }
        }
    }
    __syncthreads();

    // ---- per-node mu, rs ----
    if (tid < 200) {
        float s = *(const float*)(LDS + KC_MUS + tid * 4)
                + *(const float*)(LDS + KC_MUS + 800 + tid * 4)
                + *(const float*)(LDS + KC_MUS + 1600 + tid * 4)
                + *(const float*)(LDS + KC_MUS + 2400 + tid * 4);
        float mu = s * (1.f / 256.f);
        float var = *(const float*)(LDS + KC_VARA + tid * 4) - 256.f * mu * mu;
        *(float*)(LDS + KC_MUA + tid * 4) = mu;
        *(float*)(LDS + KC_RSA + tid * 4) = (var > 0.f) ? rsqrtf(var) : 0.f;
    }
    __syncthreads();

    // ---- epilogue: normalize + image dump in two row-halves, rowsum -> dinv, copy-out ----
    unsigned short* A16 = (unsigned short*)LDS;
#pragma unroll
    for (int half = 0; half < 2; ++half) {
        const int r0 = half ? 96 : 0;
        const int nr = half ? 104 : 96;
        const bool mine = half ? (wid >= 3 && wid < 7) : (wid < 3);
        if (mine) {
#pragma unroll
            for (int ct = 0; ct < 7; ++ct) {
                int col = ct * 32 + l31;
                if (col < 200) {
                    float muc = *(const float*)(LDS + KC_MUA + col * 4);
                    float rsc = *(const float*)(LDS + KC_RSA + col * 4);
#pragma unroll
                    for (int r = 0; r < 16; ++r) {
                        int row = wid * 32 + (r & 3) + 8 * (r >> 2) + 4 * hi;
                        if (row < 200) {
                            float mur = *(const float*)(LDS + KC_MUA + row * 4);
                            float rsr = *(const float*)(LDS + KC_RSA + row * 4);
                            float corr = (acc[ct][r] - 256.f * mur * muc) * (rsr * rsc);
                            A16[(row - r0) * ARS + col] = (unsigned short)bf16r(fabsf(corr));
                        }
                    }
                }
            }
        }
        for (int e = tid; e < nr * 16; e += 512) {       // zero pad cols 200..231
            int rr = e >> 4, pc = e & 15;
            *(unsigned*)(LDS + rr * 464 + 400 + pc * 4) = 0;
        }
        __syncthreads();
        if (tid < nr) {
            float s = 1.f;                                // the +I
#pragma unroll 4
            for (int e2 = 0; e2 < 29; ++e2) {
                short8 v = *(const short8*)(LDS + tid * 464 + e2 * 16);
#pragma unroll
                for (int j = 0; j < 8; ++j) s += bf2f((unsigned short)v[j]);
            }
            dinv[b * N + r0 + tid] = rsqrtf(s);
        }
        {
            const uint4* s4 = (const uint4*)LDS;
            uint4* g4 = (uint4*)(Abf + (size_t)b * ASAMP + (size_t)r0 * ARS);
            int cnt = nr * 29;
            for (int u = tid; u < cnt; u += 512) g4[u] = s4[u];
        }
        if (half == 0) __syncthreads();                   // image reused by half 1
    }
}

// ================= K2: fused full GCN (unchanged, known-good) =================
#define OFF_A    0
#define OFF_YT   92800
#define OFF_BUF2 122496
#define OFF_W2T  152192
#define OFF_DINV 161408
#define OFF_B1   162208
#define OFF_B2   162464
#define LDS_SZ   162720

__device__ __forceinline__ void gemm4(const unsigned char* LDSp, int aA,
                                      int bA0, int bA1, int bA2, int bA3,
                                      int nCh, f32x4* acc) {
    for (int s = 0; s < nCh; ++s) {
        int ko = s * 64;
        short8 av = *(const short8*)(LDSp + aA + ko);
        acc[0] = __builtin_amdgcn_mfma_f32_16x16x32_bf16(av, *(const short8*)(LDSp + bA0 + ko), acc[0], 0, 0, 0);
        acc[1] = __builtin_amdgcn_mfma_f32_16x16x32_bf16(av, *(const short8*)(LDSp + bA1 + ko), acc[1], 0, 0, 0);
        acc[2] = __builtin_amdgcn_mfma_f32_16x16x32_bf16(av, *(const short8*)(LDSp + bA2 + ko), acc[2], 0, 0, 0);
        acc[3] = __builtin_amdgcn_mfma_f32_16x16x32_bf16(av, *(const short8*)(LDSp + bA3 + ko), acc[3], 0, 0, 0);
    }
}

__global__ __launch_bounds__(512) void k_gcn(const unsigned short* __restrict__ Abf,
                                             const float* __restrict__ W1,
                                             const float* __restrict__ b1,
                                             const float* __restrict__ W2,
                                             const float* __restrict__ b2,
                                             const float* __restrict__ dinv,
                                             float* __restrict__ out) {
    __shared__ __align__(16) unsigned char LDS[LDS_SZ];
    const int tid = threadIdx.x;
    const int b = blockIdx.x;
    const int lane = tid & 63;
    const int l15 = lane & 15;
    const int hi = lane >> 4;
    const int wid = tid >> 6;

    {
        const uint4* gs = (const uint4*)(Abf + (size_t)b * ASAMP);
        uint4* dv4 = (uint4*)(LDS + OFF_A);
        for (int u = tid; u < 5800; u += 512) dv4[u] = gs[u];
    }
    for (int e = tid; e < N * H; e += 512) {
        int k = e >> 6, l = e & 63;
        *(unsigned short*)(LDS + OFF_BUF2 + l * 464 + k * 2) = (unsigned short)bf16r(W1[e]);
    }
    for (int e = tid; e < 64 * 16; e += 512) {
        int l = e >> 4, d = e & 15;
        *(unsigned*)(LDS + OFF_BUF2 + l * 464 + 400 + d * 4) = 0;
        *(unsigned*)(LDS + OFF_YT + l * 464 + 400 + d * 4) = 0;
    }
    for (int e = tid; e < H * H; e += 512) {
        int k = e >> 6, l = e & 63;
        *(unsigned short*)(LDS + OFF_W2T + l * 144 + k * 2) = (unsigned short)bf16r(W2[e]);
    }
    if (tid < 200) *(float*)(LDS + OFF_DINV + tid * 4) = dinv[b * N + tid];
    if (tid < 64) *(float*)(LDS + OFF_B1 + tid * 4) = b1[tid];
    else if (tid < 128) *(float*)(LDS + OFF_B2 + (tid - 64) * 4) = b2[tid - 64];
    __syncthreads();

    // ---- G1: t1 = A @ W1; y = dinv*t1 -> Yt (bf16 [l][j]) ----
    for (int rt = wid; rt < 13; rt += 8) {
        int row = rt * 16 + l15; int rowc = (row < 200) ? row : 199;
        f32x4 acc[4] = {};
        gemm4(LDS, OFF_A + rowc * 464 + hi * 16,
              OFF_BUF2 + (l15) * 464 + hi * 16,
              OFF_BUF2 + (16 + l15) * 464 + hi * 16,
              OFF_BUF2 + (32 + l15) * 464 + hi * 16,
              OFF_BUF2 + (48 + l15) * 464 + hi * 16, 7, acc);
        int j0 = rt * 16 + hi * 4;
        if (j0 < 200) {
            float d0 = *(const float*)(LDS + OFF_DINV + (j0 + 0) * 4);
            float d1 = *(const float*)(LDS + OFF_DINV + (j0 + 1) * 4);
            float d2 = *(const float*)(LDS + OFF_DINV + (j0 + 2) * 4);
            float d3 = *(const float*)(LDS + OFF_DINV + (j0 + 3) * 4);
#pragma unroll
            for (int ct = 0; ct < 4; ++ct) {
                int c = ct * 16 + l15;
                unsigned u0 = bf16r(d0 * acc[ct][0]) | (bf16r(d1 * acc[ct][1]) << 16);
                unsigned u1 = bf16r(d2 * acc[ct][2]) | (bf16r(d3 * acc[ct][3]) << 16);
                uint2 uu; uu.x = u0; uu.y = u1;
                *(uint2*)(LDS + OFF_YT + c * 464 + j0 * 2) = uu;
            }
        }
    }
    __syncthreads();

    // ---- G2: z = A @ y; h = relu(dinv_i*(z + y_i) + b1) -> BUF2 ----
    for (int rt = wid; rt < 13; rt += 8) {
        int row = rt * 16 + l15; int rowc = (row < 200) ? row : 199;
        f32x4 acc[4] = {};
        gemm4(LDS, OFF_A + rowc * 464 + hi * 16,
              OFF_YT + (l15) * 464 + hi * 16,
              OFF_YT + (16 + l15) * 464 + hi * 16,
              OFF_YT + (32 + l15) * 464 + hi * 16,
              OFF_YT + (48 + l15) * 464 + hi * 16, 7, acc);
#pragma unroll
        for (int ct = 0; ct < 4; ++ct) {
            int c = ct * 16 + l15;
            float bias = *(const float*)(LDS + OFF_B1 + c * 4);
#pragma unroll
            for (int r = 0; r < 4; ++r) {
                int i = rt * 16 + hi * 4 + r;
                if (i < 200) {
                    float dv = *(const float*)(LDS + OFF_DINV + i * 4);
                    float yi = bf2f(*(const unsigned short*)(LDS + OFF_YT + c * 464 + i * 2));
                    float v = dv * (acc[ct][r] + yi) + bias;
                    *(unsigned short*)(LDS + OFF_BUF2 + i * 144 + c * 2) =
                        (unsigned short)bf16r(fmaxf(v, 0.f));
                }
            }
        }
    }
    __syncthreads();

    // ---- G3: t2 = h @ W2; y2 = dinv*t2 -> Yt ----
    for (int rt = wid; rt < 13; rt += 8) {
        int row = rt * 16 + l15; int rowc = (row < 200) ? row : 199;
        f32x4 acc[4] = {};
        gemm4(LDS, OFF_BUF2 + rowc * 144 + hi * 16,
              OFF_W2T + (l15) * 144 + hi * 16,
              OFF_W2T + (16 + l15) * 144 + hi * 16,
              OFF_W2T + (32 + l15) * 144 + hi * 16,
              OFF_W2T + (48 + l15) * 144 + hi * 16, 2, acc);
        int j0 = rt * 16 + hi * 4;
        if (j0 < 200) {
            float d0 = *(const float*)(LDS + OFF_DINV + (j0 + 0) * 4);
            float d1 = *(const float*)(LDS + OFF_DINV + (j0 + 1) * 4);
            float d2 = *(const float*)(LDS + OFF_DINV + (j0 + 2) * 4);
            float d3 = *(const float*)(LDS + OFF_DINV + (j0 + 3) * 4);
#pragma unroll
            for (int ct = 0; ct < 4; ++ct) {
                int c = ct * 16 + l15;
                unsigned u0 = bf16r(d0 * acc[ct][0]) | (bf16r(d1 * acc[ct][1]) << 16);
                unsigned u1 = bf16r(d2 * acc[ct][2]) | (bf16r(d3 * acc[ct][3]) << 16);
                uint2 uu; uu.x = u0; uu.y = u1;
                *(uint2*)(LDS + OFF_YT + c * 464 + j0 * 2) = uu;
            }
        }
    }
    __syncthreads();

    // ---- G4: z2 = A @ y2; out = relu(dinv_i*(z2 + y2_i) + b2) ----
    for (int rt = wid; rt < 13; rt += 8) {
        int row = rt * 16 + l15; int rowc = (row < 200) ? row : 199;
        f32x4 acc[4] = {};
        gemm4(LDS, OFF_A + rowc * 464 + hi * 16,
              OFF_YT + (l15) * 464 + hi * 16,
              OFF_YT + (16 + l15) * 464 + hi * 16,
              OFF_YT + (32 + l15) * 464 + hi * 16,
              OFF_YT + (48 + l15) * 464 + hi * 16, 7, acc);
#pragma unroll
        for (int ct = 0; ct < 4; ++ct) {
            int c = ct * 16 + l15;
            float bias = *(const float*)(LDS + OFF_B2 + c * 4);
#pragma unroll
            for (int r = 0; r < 4; ++r) {
                int i = rt * 16 + hi * 4 + r;
                if (i < 200) {
                    float dv = *(const float*)(LDS + OFF_DINV + i * 4);
                    float yi = bf2f(*(const unsigned short*)(LDS + OFF_YT + c * 464 + i * 2));
                    float v = dv * (acc[ct][r] + yi) + bias;
                    out[((size_t)b * N + i) * H + c] = fmaxf(v, 0.f);
                }
            }
        }
    }
}

extern "C" void kernel_launch(void* const* d_in, const int* in_sizes, int n_in,
                              void* d_out, int out_size, void* d_ws, size_t ws_size,
                              hipStream_t stream) {
    const float* data = (const float*)d_in[0];
    const float* W1   = (const float*)d_in[1];
    const float* b1   = (const float*)d_in[2];
    const float* W2   = (const float*)d_in[3];
    const float* b2   = (const float*)d_in[4];
    float* out = (float*)d_out;

    unsigned short* Abf = (unsigned short*)d_ws;          // 512*46400 bf16 = 47.5 MB
    float* dinv = (float*)(Abf + (size_t)B * ASAMP);      // 102400 f32 -> total ~47.9 MB

    hipLaunchKernelGGL(k_corr, dim3(B), dim3(512), 0, stream, data, Abf, dinv);
    hipLaunchKernelGGL(k_gcn,  dim3(B), dim3(512), 0, stream, Abf, W1, b1, W2, b2, dinv, out);
}

// Round 9
// 76.592 us; speedup vs baseline: 1.3855x; 1.3855x over previous
//
#include <hip/hip_runtime.h>
#include <math.h>

#define B 512
#define T 256
#define N 200
#define H 64
#define TN (T*N)     // 51200

#define ARS 232              // A image row stride in bf16 (464 B)
#define XTRS 80              // Xt row stride bytes (32 bf16 + 16B pad; 5 slots, odd -> skew)

// ---- fused-kernel LDS map (byte offsets), sequenced by liveness ----
// corr phase: S0..S3 staging ring [0,102400) | Xt0/Xt1 [102400,134400)
//             stats [92800,98400)  (written only AFTER S3's last read; S-region
//             and image are dead/unwritten there during the stats window)
// gcn  phase: image [0,92800) | YT | BUF2(W1T->h) | W2T | DINV | B1 | B2
#define LS_S(i)  (25600*(i))            // 4 x [32 t][200 n] f32
#define LS_XT(i) (102400 + 16000*(i))   // 2 x [200 n][32 t] bf16 stride 80
#define LS_MUS   92800                  // 800 f32 mu partials (4 sets of 200)
#define LS_VARA  96000                  // 200 f32 raw diag
#define LS_MUA   96800
#define LS_RSA   97600                  // ..98400
#define LS_YT    92800                  // 64 x 464 B  (written only from G1 on; pads
                                        //  zeroed in dinv section, after stats die)
#define LS_BUF2  122496                 // 64 x 464 B  (W1T, then h)
#define LS_W2T   152192                 // 64 x 144 B
#define LS_DINV  161408                 // 200 f32
#define LS_B1    162208
#define LS_B2    162464
#define LS_SZ    162720

typedef short short8 __attribute__((ext_vector_type(8)));
typedef float f32x4 __attribute__((ext_vector_type(4)));
typedef float f32x16 __attribute__((ext_vector_type(16)));

__device__ __forceinline__ unsigned bf16r(float x) {
    unsigned u = __float_as_uint(x);
    return (u + 0x7fffu + ((u >> 16) & 1u)) >> 16;   // round-to-nearest-even
}
__device__ __forceinline__ float bf2f(unsigned short u) {
    return __uint_as_float(((unsigned)u) << 16);
}
__device__ __forceinline__ void gll16(const void* g, void* l) {
    __builtin_amdgcn_global_load_lds(
        (const __attribute__((address_space(1))) unsigned*)g,
        (__attribute__((address_space(3))) unsigned*)l, 16, 0, 0);
}

// counted waitcnt: loads stay in flight ACROSS the raw barrier (T3+T4)
#define WAITV(n) asm volatile("s_waitcnt vmcnt(" #n ") lgkmcnt(0)" ::: "memory")

__device__ __forceinline__ void gemm4(const unsigned char* LDSp, int aA,
                                      int bA0, int bA1, int bA2, int bA3,
                                      int nCh, f32x4* acc) {
    for (int s = 0; s < nCh; ++s) {
        int ko = s * 64;
        short8 av = *(const short8*)(LDSp + aA + ko);
        acc[0] = __builtin_amdgcn_mfma_f32_16x16x32_bf16(av, *(const short8*)(LDSp + bA0 + ko), acc[0], 0, 0, 0);
        acc[1] = __builtin_amdgcn_mfma_f32_16x16x32_bf16(av, *(const short8*)(LDSp + bA1 + ko), acc[1], 0, 0, 0);
        acc[2] = __builtin_amdgcn_mfma_f32_16x16x32_bf16(av, *(const short8*)(LDSp + bA2 + ko), acc[2], 0, 0, 0);
        acc[3] = __builtin_amdgcn_mfma_f32_16x16x32_bf16(av, *(const short8*)(LDSp + bA3 + ko), acc[3], 0, 0, 0);
    }
}

__global__ __launch_bounds__(512) void k_fused(const float* __restrict__ data,
                                               const float* __restrict__ W1,
                                               const float* __restrict__ b1f,
                                               const float* __restrict__ W2,
                                               const float* __restrict__ b2f,
                                               float* __restrict__ out) {
    __shared__ __align__(16) unsigned char LDS[LS_SZ];
    const int tid  = threadIdx.x;
    const int b    = blockIdx.x;
    const int lane = tid & 63;
    const int wid  = tid >> 6;
    const int l31  = lane & 31;
    const int hi32 = lane >> 5;
    const int l15  = lane & 15;
    const int hi16 = lane >> 4;
    const float4* db4 = (const float4*)(data + (size_t)b * TN);

    f32x16 acc[7] = {};
    float mu0 = 0.f, mu1 = 0.f;
    const int n0 = tid % 200, q0 = tid / 200;                  // transpose unit 0
    const int n1 = (tid + 512) % 200, q1 = (tid + 512) / 200;  // unit 1 (tid<288)

    int arow = wid * 32 + l31; if (arow > 199) arow = 199;
    int bcc[7];
#pragma unroll
    for (int ct = 0; ct < 7; ++ct) { int c2 = ct * 32 + l31; bcc[ct] = (c2 > 199) ? 199 : c2; }

    // stage chunk cc into 4-deep ring: 25 x 1KB gll16; waves 0-5 issue 4, wave 6 one, wave 7 none
    auto stage = [&](int cc) {
        const float4* src = db4 + cc * 1600;
        unsigned char* dst = LDS + LS_S(cc & 3);
#pragma unroll
        for (int i = 0; i < 4; ++i) {
            int p = (wid << 2) + i;
            if (p < 25) {
                int idx = (p << 6) + lane;
                gll16(src + idx, dst + idx * 16);
            }
        }
    };
    // transpose chunk c: S[c&3] f32 [32t][200n] -> Xt[c&1] bf16 [200n][32t], mu partials in regs
    auto transpose = [&](int c) {
        const float* Sc = (const float*)(LDS + LS_S(c & 3));
        unsigned char* Xc = LDS + LS_XT(c & 1);
        {
            const float* s0 = Sc + (q0 * 8) * 200 + n0;
            unsigned u[4]; float a = 0.f;
#pragma unroll
            for (int j = 0; j < 4; ++j) {
                unsigned b0 = bf16r(s0[(2 * j) * 200]);
                unsigned b1 = bf16r(s0[(2 * j + 1) * 200]);
                a += bf2f((unsigned short)b0) + bf2f((unsigned short)b1);
                u[j] = b0 | (b1 << 16);
            }
            mu0 += a;
            uint4 pk; pk.x = u[0]; pk.y = u[1]; pk.z = u[2]; pk.w = u[3];
            *(uint4*)(Xc + n0 * XTRS + q0 * 16) = pk;
        }
        if (tid < 288) {
            const float* s0 = Sc + (q1 * 8) * 200 + n1;
            unsigned u[4]; float a = 0.f;
#pragma unroll
            for (int j = 0; j < 4; ++j) {
                unsigned b0 = bf16r(s0[(2 * j) * 200]);
                unsigned b1 = bf16r(s0[(2 * j + 1) * 200]);
                a += bf2f((unsigned short)b0) + bf2f((unsigned short)b1);
                u[j] = b0 | (b1 << 16);
            }
            mu1 += a;
            uint4 pk; pk.x = u[0]; pk.y = u[1]; pk.z = u[2]; pk.w = u[3];
            *(uint4*)(Xc + n1 * XTRS + q1 * 16) = pk;
        }
    };
    auto domfma = [&](int cp) {
        if (wid < 7) {
            const unsigned char* Xp = LDS + LS_XT(cp & 1);
#pragma unroll
            for (int kc = 0; kc < 2; ++kc) {
                short8 a = *(const short8*)(Xp + arow * XTRS + kc * 32 + hi32 * 16);
#pragma unroll
                for (int ct = 0; ct < 7; ++ct) {
                    short8 bb = *(const short8*)(Xp + bcc[ct] * XTRS + kc * 32 + hi32 * 16);
                    acc[ct] = __builtin_amdgcn_mfma_f32_32x32x16_bf16(a, bb, acc[ct], 0, 0, 0);
                }
            }
        }
    };

    // ---- corr K-loop: 2-deep prefetch, counted vmcnt, raw barriers ----
    // Ring safety: stage(c+2) writes S[(c+2)&3]; its previous reader transpose(c-2)
    // is separated by barrier(c-1) -> no write-while-read (the round-8 3-ring raced).
    stage(0); stage(1);
#pragma unroll
    for (int c = 0; c < 8; ++c) {
        if (c < 6) stage(c + 2);
        if (wid < 6)        { if (c < 6) WAITV(8); else if (c == 6) WAITV(4); else WAITV(0); }
        else if (wid == 6)  { if (c < 6) WAITV(2); else if (c == 6) WAITV(1); else WAITV(0); }
        else                { WAITV(0); }
        __builtin_amdgcn_sched_barrier(0);
        __builtin_amdgcn_s_barrier();        // S[c] + Xt[c-1] now valid for all waves
        __builtin_amdgcn_sched_barrier(0);
        if (c > 0) domfma(c - 1);
        transpose(c);
    }
    asm volatile("s_waitcnt lgkmcnt(0)" ::: "memory");
    __builtin_amdgcn_s_barrier();            // publish Xt[7]
    __builtin_amdgcn_sched_barrier(0);
    domfma(7);
    asm volatile("s_waitcnt lgkmcnt(0)" ::: "memory");
    __builtin_amdgcn_s_barrier();            // Xt dead -> BUF2 (overlaps Xt1) writable
    __builtin_amdgcn_sched_barrier(0);

    // ---- weight staging + mu partials + raw diag ----
    // Stats region [92800,98400) is disjoint from every write in this section
    // (BUF2/W2T/B1/B2 all >= 122496). YT pad zeroing is DEFERRED (round-8 bug #1).
    for (int e = tid; e < N * H; e += 512) {              // W1^T -> BUF2
        int k = e >> 6, l = e & 63;
        *(unsigned short*)(LDS + LS_BUF2 + l * 464 + k * 2) = (unsigned short)bf16r(W1[e]);
    }
    for (int e = tid; e < 64 * 16; e += 512) {            // W1T pads = 0
        int l = e >> 4, d = e & 15;
        *(unsigned*)(LDS + LS_BUF2 + l * 464 + 400 + d * 4) = 0;
    }
    for (int e = tid; e < H * H; e += 512) {              // W2^T
        int k = e >> 6, l = e & 63;
        *(unsigned short*)(LDS + LS_W2T + l * 144 + k * 2) = (unsigned short)bf16r(W2[e]);
    }
    if (tid < 64) *(float*)(LDS + LS_B1 + tid * 4) = b1f[tid];
    else if (tid < 128) *(float*)(LDS + LS_B2 + (tid - 64) * 4) = b2f[tid - 64];

    *(float*)(LDS + LS_MUS + tid * 4) = mu0;              // slot q0*200+n0 == tid
    if (tid < 288) *(float*)(LDS + LS_MUS + (tid + 512) * 4) = mu1;
#pragma unroll
    for (int ct = 0; ct < 7; ++ct) {
        if (wid == ct) {
#pragma unroll
            for (int r = 0; r < 16; ++r) {
                int rowin = (r & 3) + 8 * (r >> 2) + 4 * hi32;
                int n = ct * 32 + rowin;
                if (l31 == rowin && n < 200)
                    *(float*)(LDS + LS_VARA + n * 4) = acc[ct][r];   // S_nn
            }
        }
    }
    __syncthreads();

    // ---- per-node mu, rs ----
    if (tid < 200) {
        float s = *(const float*)(LDS + LS_MUS + tid * 4)
                + *(const float*)(LDS + LS_MUS + 800 + tid * 4)
                + *(const float*)(LDS + LS_MUS + 1600 + tid * 4)
                + *(const float*)(LDS + LS_MUS + 2400 + tid * 4);
        float mu = s * (1.f / 256.f);
        float var = *(const float*)(LDS + LS_VARA + tid * 4) - 256.f * mu * mu;
        *(float*)(LDS + LS_MUA + tid * 4) = mu;
        *(float*)(LDS + LS_RSA + tid * 4) = (var > 0.f) ? rsqrtf(var) : 0.f;
    }
    __syncthreads();

    // ---- epilogue: |corr| -> image [200][232] bf16 at LDS[0) + image pads ----
    unsigned short* A16 = (unsigned short*)LDS;
    if (wid < 7) {
#pragma unroll
        for (int ct = 0; ct < 7; ++ct) {
            int col = ct * 32 + l31;
            if (col < 200) {
                float muc = *(const float*)(LDS + LS_MUA + col * 4);
                float rsc = *(const float*)(LDS + LS_RSA + col * 4);
#pragma unroll
                for (int r = 0; r < 16; ++r) {
                    int row = wid * 32 + (r & 3) + 8 * (r >> 2) + 4 * hi32;
                    if (row < 200) {
                        float mur = *(const float*)(LDS + LS_MUA + row * 4);
                        float rsr = *(const float*)(LDS + LS_RSA + row * 4);
                        float corr = (acc[ct][r] - 256.f * mur * muc) * (rsr * rsc);
                        A16[row * ARS + col] = (unsigned short)bf16r(fabsf(corr));
                    }
                }
            }
        }
    }
    for (int e = tid; e < 3200; e += 512) {               // image pad cols 200..231 = 0
        int row = e >> 4, pc = e & 15;
        *(unsigned*)(LDS + row * 464 + 400 + pc * 4) = 0;
    }
    __syncthreads();                                      // stats dead from here on

    // ---- row sums -> dinv (LDS only) + deferred YT pad zeroing ----
    if (tid < 200) {
        float s = 1.f;                                     // the +I
#pragma unroll 4
        for (int e2 = 0; e2 < 29; ++e2) {
            short8 v = *(const short8*)(LDS + tid * 464 + e2 * 16);
#pragma unroll
            for (int j = 0; j < 8; ++j) s += bf2f((unsigned short)v[j]);
        }
        *(float*)(LDS + LS_DINV + tid * 4) = rsqrtf(s);
    }
    for (int e = tid; e < 64 * 16; e += 512) {            // YT pads = 0 (stats now dead)
        int l = e >> 4, d = e & 15;
        *(unsigned*)(LDS + LS_YT + l * 464 + 400 + d * 4) = 0;
    }
    __syncthreads();

    // ================= GCN (proven structure, A/dinv resident) =================
    // ---- G1: t1 = A @ W1; y = dinv*t1 -> YT (bf16 [l][j]) ----
    for (int rt = wid; rt < 13; rt += 8) {
        int row = rt * 16 + l15; int rowc = (row < 200) ? row : 199;
        f32x4 ac[4] = {};
        gemm4(LDS, rowc * 464 + hi16 * 16,
              LS_BUF2 + (l15) * 464 + hi16 * 16,
              LS_BUF2 + (16 + l15) * 464 + hi16 * 16,
              LS_BUF2 + (32 + l15) * 464 + hi16 * 16,
              LS_BUF2 + (48 + l15) * 464 + hi16 * 16, 7, ac);
        int j0 = rt * 16 + hi16 * 4;
        if (j0 < 200) {
            float d0 = *(const float*)(LDS + LS_DINV + (j0 + 0) * 4);
            float d1 = *(const float*)(LDS + LS_DINV + (j0 + 1) * 4);
            float d2 = *(const float*)(LDS + LS_DINV + (j0 + 2) * 4);
            float d3 = *(const float*)(LDS + LS_DINV + (j0 + 3) * 4);
#pragma unroll
            for (int ct = 0; ct < 4; ++ct) {
                int c = ct * 16 + l15;
                unsigned u0 = bf16r(d0 * ac[ct][0]) | (bf16r(d1 * ac[ct][1]) << 16);
                unsigned u1 = bf16r(d2 * ac[ct][2]) | (bf16r(d3 * ac[ct][3]) << 16);
                uint2 uu; uu.x = u0; uu.y = u1;
                *(uint2*)(LDS + LS_YT + c * 464 + j0 * 2) = uu;
            }
        }
    }
    __syncthreads();

    // ---- G2: z = A @ y; h = relu(dinv_i*(z + y_i) + b1) -> BUF2 ----
    for (int rt = wid; rt < 13; rt += 8) {
        int row = rt * 16 + l15; int rowc = (row < 200) ? row : 199;
        f32x4 ac[4] = {};
        gemm4(LDS, rowc * 464 + hi16 * 16,
              LS_YT + (l15) * 464 + hi16 * 16,
              LS_YT + (16 + l15) * 464 + hi16 * 16,
              LS_YT + (32 + l15) * 464 + hi16 * 16,
              LS_YT + (48 + l15) * 464 + hi16 * 16, 7, ac);
#pragma unroll
        for (int ct = 0; ct < 4; ++ct) {
            int c = ct * 16 + l15;
            float bias = *(const float*)(LDS + LS_B1 + c * 4);
#pragma unroll
            for (int r = 0; r < 4; ++r) {
                int i = rt * 16 + hi16 * 4 + r;
                if (i < 200) {
                    float dv = *(const float*)(LDS + LS_DINV + i * 4);
                    float yi = bf2f(*(const unsigned short*)(LDS + LS_YT + c * 464 + i * 2));
                    float v = dv * (ac[ct][r] + yi) + bias;
                    *(unsigned short*)(LDS + LS_BUF2 + i * 144 + c * 2) =
                        (unsigned short)bf16r(fmaxf(v, 0.f));
                }
            }
        }
    }
    __syncthreads();

    // ---- G3: t2 = h @ W2; y2 = dinv*t2 -> YT ----
    for (int rt = wid; rt < 13; rt += 8) {
        int row = rt * 16 + l15; int rowc = (row < 200) ? row : 199;
        f32x4 ac[4] = {};
        gemm4(LDS, LS_BUF2 + rowc * 144 + hi16 * 16,
              LS_W2T + (l15) * 144 + hi16 * 16,
              LS_W2T + (16 + l15) * 144 + hi16 * 16,
              LS_W2T + (32 + l15) * 144 + hi16 * 16,
              LS_W2T + (48 + l15) * 144 + hi16 * 16, 2, ac);
        int j0 = rt * 16 + hi16 * 4;
        if (j0 < 200) {
            float d0 = *(const float*)(LDS + LS_DINV + (j0 + 0) * 4);
            float d1 = *(const float*)(LDS + LS_DINV + (j0 + 1) * 4);
            float d2 = *(const float*)(LDS + LS_DINV + (j0 + 2) * 4);
            float d3 = *(const float*)(LDS + LS_DINV + (j0 + 3) * 4);
#pragma unroll
            for (int ct = 0; ct < 4; ++ct) {
                int c = ct * 16 + l15;
                unsigned u0 = bf16r(d0 * ac[ct][0]) | (bf16r(d1 * ac[ct][1]) << 16);
                unsigned u1 = bf16r(d2 * ac[ct][2]) | (bf16r(d3 * ac[ct][3]) << 16);
                uint2 uu; uu.x = u0; uu.y = u1;
                *(uint2*)(LDS + LS_YT + c * 464 + j0 * 2) = uu;
            }
        }
    }
    __syncthreads();

    // ---- G4: z2 = A @ y2; out = relu(dinv_i*(z2 + y2_i) + b2) ----
    for (int rt = wid; rt < 13; rt += 8) {
        int row = rt * 16 + l15; int rowc = (row < 200) ? row : 199;
        f32x4 ac[4] = {};
        gemm4(LDS, rowc * 464 + hi16 * 16,
              LS_YT + (l15) * 464 + hi16 * 16,
              LS_YT + (16 + l15) * 464 + hi16 * 16,
              LS_YT + (32 + l15) * 464 + hi16 * 16,
              LS_YT + (48 + l15) * 464 + hi16 * 16, 7, ac);
#pragma unroll
        for (int ct = 0; ct < 4; ++ct) {
            int c = ct * 16 + l15;
            float bias = *(const float*)(LDS + LS_B2 + c * 4);
#pragma unroll
            for (int r = 0; r < 4; ++r) {
                int i = rt * 16 + hi16 * 4 + r;
                if (i < 200) {
                    float dv = *(const float*)(LDS + LS_DINV + i * 4);
                    float yi = bf2f(*(const unsigned short*)(LDS + LS_YT + c * 464 + i * 2));
                    float v = dv * (ac[ct][r] + yi) + bias;
                    out[((size_t)b * N + i) * H + c] = fmaxf(v, 0.f);
                }
            }
        }
    }
}

extern "C" void kernel_launch(void* const* d_in, const int* in_sizes, int n_in,
                              void* d_out, int out_size, void* d_ws, size_t ws_size,
                              hipStream_t stream) {
    const float* data = (const float*)d_in[0];
    const float* W1   = (const float*)d_in[1];
    const float* b1   = (const float*)d_in[2];
    const float* W2   = (const float*)d_in[3];
    const float* b2   = (const float*)d_in[4];
    float* out = (float*)d_out;

    hipLaunchKernelGGL(k_fused, dim3(B), dim3(512), 0, stream, data, W1, b1, W2, b2, out);
}

// Round 10
// 67.220 us; speedup vs baseline: 1.5787x; 1.1394x over previous
//
#include <hip/hip_runtime.h>
#include <math.h>

#define B 512
#define T 256
#define N 200
#define H 64
#define TN (T*N)     // 51200
#define NT 1024      // 16 waves -> 4 waves/SIMD (round-9 was 512 -> 2/SIMD, stall-bound)

#define ARS 232              // A image row stride in bf16 (464 B)
#define XTRS 80              // Xt row stride bytes (32 bf16 + 16B pad; 5 slots, odd -> skew)

// ---- fused-kernel LDS map (byte offsets), sequenced by liveness (proven round 9) ----
#define LS_S(i)  (25600*(i))            // 4 x [32 t][200 n] f32 staging ring
#define LS_XT(i) (102400 + 16000*(i))   // 2 x [200 n][32 t] bf16 stride 80
#define LS_MUS   92800                  // 800 f32 mu partials (4 sets of 200)
#define LS_VARA  96000                  // 200 f32 raw diag
#define LS_MUA   96800
#define LS_RSA   97600                  // ..98400
#define LS_YT    92800                  // 64 x 464 B  (pads zeroed AFTER stats die)
#define LS_BUF2  122496                 // 64 x 464 B  (W1T, then h; overlaps dead Xt1)
#define LS_W2T   152192                 // 64 x 144 B
#define LS_DINV  161408                 // 200 f32
#define LS_B1    162208
#define LS_B2    162464
#define LS_SZ    162720

typedef short short8 __attribute__((ext_vector_type(8)));
typedef float f32x4 __attribute__((ext_vector_type(4)));
typedef float f32x16 __attribute__((ext_vector_type(16)));

__device__ __forceinline__ unsigned bf16r(float x) {
    unsigned u = __float_as_uint(x);
    return (u + 0x7fffu + ((u >> 16) & 1u)) >> 16;   // round-to-nearest-even
}
__device__ __forceinline__ float bf2f(unsigned short u) {
    return __uint_as_float(((unsigned)u) << 16);
}
__device__ __forceinline__ void gll16(const void* g, void* l) {
    __builtin_amdgcn_global_load_lds(
        (const __attribute__((address_space(1))) unsigned*)g,
        (__attribute__((address_space(3))) unsigned*)l, 16, 0, 0);
}

// counted waitcnt: loads stay in flight ACROSS the raw barrier (T3+T4)
#define WAITV(n) asm volatile("s_waitcnt vmcnt(" #n ") lgkmcnt(0)" ::: "memory")

__device__ __forceinline__ void gemm4(const unsigned char* LDSp, int aA,
                                      int bA0, int bA1, int bA2, int bA3,
                                      int nCh, f32x4* acc) {
    for (int s = 0; s < nCh; ++s) {
        int ko = s * 64;
        short8 av = *(const short8*)(LDSp + aA + ko);
        acc[0] = __builtin_amdgcn_mfma_f32_16x16x32_bf16(av, *(const short8*)(LDSp + bA0 + ko), acc[0], 0, 0, 0);
        acc[1] = __builtin_amdgcn_mfma_f32_16x16x32_bf16(av, *(const short8*)(LDSp + bA1 + ko), acc[1], 0, 0, 0);
        acc[2] = __builtin_amdgcn_mfma_f32_16x16x32_bf16(av, *(const short8*)(LDSp + bA2 + ko), acc[2], 0, 0, 0);
        acc[3] = __builtin_amdgcn_mfma_f32_16x16x32_bf16(av, *(const short8*)(LDSp + bA3 + ko), acc[3], 0, 0, 0);
    }
}

__global__ __launch_bounds__(NT) void k_fused(const float* __restrict__ data,
                                              const float* __restrict__ W1,
                                              const float* __restrict__ b1f,
                                              const float* __restrict__ W2,
                                              const float* __restrict__ b2f,
                                              float* __restrict__ out) {
    __shared__ __align__(16) unsigned char LDS[LS_SZ];
    const int tid  = threadIdx.x;
    const int b    = blockIdx.x;
    const int lane = tid & 63;
    const int wid  = tid >> 6;          // 0..15
    const int l31  = lane & 31;
    const int hi32 = lane >> 5;
    const int l15  = lane & 15;
    const int hi16 = lane >> 4;
    const float4* db4 = (const float4*)(data + (size_t)b * TN);

    f32x16 acc0 = {}, acc1 = {};
    float mu0 = 0.f;
    const int n0 = tid % 200, q0 = tid / 200;   // transpose unit (tid<800 only)

    // ---- symmetric tile assignment: 28 upper-tri 32x32 tiles over 16 waves ----
    // wave w: tile0 = w; tile1 = 16+(15-w) for w>=4 (waves doing least transpose
    // take the extra tile). Diag tiles reuse the A fragment as B.
    int ti0 = 0, tj0 = 0, ti1 = 0, tj1 = 0;
    {
        int k = 0;
        for (int i = 0; i < 7; ++i)
            for (int j = i; j < 7; ++j) {
                if (k == wid)                       { ti0 = i; tj0 = j; }
                if (wid >= 4 && k == 16 + 15 - wid) { ti1 = i; tj1 = j; }
                ++k;
            }
    }
    const bool has1 = (wid >= 4);
    const bool d0 = (ti0 == tj0), d1 = (ti1 == tj1);
    int ar0 = ti0 * 32 + l31; if (ar0 > 199) ar0 = 199;
    int bc0 = tj0 * 32 + l31; if (bc0 > 199) bc0 = 199;
    int ar1 = ti1 * 32 + l31; if (ar1 > 199) ar1 = 199;
    int bc1 = tj1 * 32 + l31; if (bc1 > 199) bc1 = 199;

    // stage chunk cc into 4-deep ring: 25 x 1KB gll16; waves 0-11 issue 2, wave 12 one
    auto stage = [&](int cc) {
        const float4* src = db4 + cc * 1600;
        unsigned char* dst = LDS + LS_S(cc & 3);
#pragma unroll
        for (int i = 0; i < 2; ++i) {
            int p = (wid << 1) + i;
            if (p < 25) {
                int idx = (p << 6) + lane;
                gll16(src + idx, dst + idx * 16);
            }
        }
    };
    // transpose chunk c: S[c&3] f32 [32t][200n] -> Xt[c&1] bf16 [200n][32t]
    auto transpose = [&](int c) {
        if (tid < 800) {
            const float* s0 = (const float*)(LDS + LS_S(c & 3)) + (q0 * 8) * 200 + n0;
            unsigned u[4]; float a = 0.f;
#pragma unroll
            for (int j = 0; j < 4; ++j) {
                unsigned b0 = bf16r(s0[(2 * j) * 200]);
                unsigned b1 = bf16r(s0[(2 * j + 1) * 200]);
                a += bf2f((unsigned short)b0) + bf2f((unsigned short)b1);
                u[j] = b0 | (b1 << 16);
            }
            mu0 += a;
            uint4 pk; pk.x = u[0]; pk.y = u[1]; pk.z = u[2]; pk.w = u[3];
            *(uint4*)(LDS + LS_XT(c & 1) + n0 * XTRS + q0 * 16) = pk;
        }
    };
    auto domfma = [&](int cp) {
        const unsigned char* Xp = LDS + LS_XT(cp & 1);
#pragma unroll
        for (int kc = 0; kc < 2; ++kc) {
            int kb = kc * 32 + hi32 * 16;
            short8 a0 = *(const short8*)(Xp + ar0 * XTRS + kb);
            short8 b0 = d0 ? a0 : *(const short8*)(Xp + bc0 * XTRS + kb);
            acc0 = __builtin_amdgcn_mfma_f32_32x32x16_bf16(a0, b0, acc0, 0, 0, 0);
            if (has1) {
                short8 a1 = *(const short8*)(Xp + ar1 * XTRS + kb);
                short8 b1 = d1 ? a1 : *(const short8*)(Xp + bc1 * XTRS + kb);
                acc1 = __builtin_amdgcn_mfma_f32_32x32x16_bf16(a1, b1, acc1, 0, 0, 0);
            }
        }
    };

    // ---- corr K-loop: 2-deep prefetch, counted vmcnt, raw barriers (proven) ----
    stage(0); stage(1);
#pragma unroll
    for (int c = 0; c < 8; ++c) {
        if (c < 6) stage(c + 2);
        if (wid < 12)       { if (c < 6) WAITV(4); else if (c == 6) WAITV(2); else WAITV(0); }
        else if (wid == 12) { if (c < 6) WAITV(2); else if (c == 6) WAITV(1); else WAITV(0); }
        else                { WAITV(0); }
        __builtin_amdgcn_sched_barrier(0);
        __builtin_amdgcn_s_barrier();        // S[c] + Xt[c-1] now valid for all waves
        __builtin_amdgcn_sched_barrier(0);
        if (c > 0) domfma(c - 1);
        transpose(c);
    }
    asm volatile("s_waitcnt lgkmcnt(0)" ::: "memory");
    __builtin_amdgcn_s_barrier();            // publish Xt[7]
    __builtin_amdgcn_sched_barrier(0);
    domfma(7);
    asm volatile("s_waitcnt lgkmcnt(0)" ::: "memory");
    __builtin_amdgcn_s_barrier();            // Xt dead -> BUF2 (overlaps Xt1) writable
    __builtin_amdgcn_sched_barrier(0);

    // ---- weight staging + mu partials + raw diag (stats region disjoint from writes) ----
    for (int e = tid; e < N * H; e += NT) {               // W1^T -> BUF2
        int k = e >> 6, l = e & 63;
        *(unsigned short*)(LDS + LS_BUF2 + l * 464 + k * 2) = (unsigned short)bf16r(W1[e]);
    }
    for (int e = tid; e < 64 * 16; e += NT) {             // W1T pads = 0
        int l = e >> 4, d = e & 15;
        *(unsigned*)(LDS + LS_BUF2 + l * 464 + 400 + d * 4) = 0;
    }
    for (int e = tid; e < H * H; e += NT) {               // W2^T
        int k = e >> 6, l = e & 63;
        *(unsigned short*)(LDS + LS_W2T + l * 144 + k * 2) = (unsigned short)bf16r(W2[e]);
    }
    if (tid < 64) *(float*)(LDS + LS_B1 + tid * 4) = b1f[tid];
    else if (tid < 128) *(float*)(LDS + LS_B2 + (tid - 64) * 4) = b2f[tid - 64];

    if (tid < 800) *(float*)(LDS + LS_MUS + tid * 4) = mu0;   // slot q0*200+n0 == tid
    if (d0) {
#pragma unroll
        for (int r = 0; r < 16; ++r) {
            int rowin = (r & 3) + 8 * (r >> 2) + 4 * hi32;
            int n = ti0 * 32 + rowin;
            if (l31 == rowin && n < 200)
                *(float*)(LDS + LS_VARA + n * 4) = acc0[r];   // S_nn
        }
    }
    if (has1 && d1) {
#pragma unroll
        for (int r = 0; r < 16; ++r) {
            int rowin = (r & 3) + 8 * (r >> 2) + 4 * hi32;
            int n = ti1 * 32 + rowin;
            if (l31 == rowin && n < 200)
                *(float*)(LDS + LS_VARA + n * 4) = acc1[r];
        }
    }
    __syncthreads();

    // ---- per-node mu, rs ----
    if (tid < 200) {
        float s = *(const float*)(LDS + LS_MUS + tid * 4)
                + *(const float*)(LDS + LS_MUS + 800 + tid * 4)
                + *(const float*)(LDS + LS_MUS + 1600 + tid * 4)
                + *(const float*)(LDS + LS_MUS + 2400 + tid * 4);
        float mu = s * (1.f / 256.f);
        float var = *(const float*)(LDS + LS_VARA + tid * 4) - 256.f * mu * mu;
        *(float*)(LDS + LS_MUA + tid * 4) = mu;
        *(float*)(LDS + LS_RSA + tid * 4) = (var > 0.f) ? rsqrtf(var) : 0.f;
    }
    __syncthreads();

    // ---- epilogue: |corr| -> image [200][232] bf16 (upper tile + mirror) + pads ----
    unsigned short* A16 = (unsigned short*)LDS;
    auto epi = [&](const f32x16& ac, int ib, int jb) {
        int col = jb + l31;
        if (col < 200) {
            float muc = *(const float*)(LDS + LS_MUA + col * 4);
            float rsc = *(const float*)(LDS + LS_RSA + col * 4);
#pragma unroll
            for (int r = 0; r < 16; ++r) {
                int row = ib + (r & 3) + 8 * (r >> 2) + 4 * hi32;
                if (row < 200) {
                    float mur = *(const float*)(LDS + LS_MUA + row * 4);
                    float rsr = *(const float*)(LDS + LS_RSA + row * 4);
                    float corr = (ac[r] - 256.f * mur * muc) * (rsr * rsc);
                    unsigned short bv = (unsigned short)bf16r(fabsf(corr));
                    A16[row * ARS + col] = bv;
                    if (ib != jb) A16[col * ARS + row] = bv;   // symmetric mirror
                }
            }
        }
    };
    epi(acc0, ti0 * 32, tj0 * 32);
    if (has1) epi(acc1, ti1 * 32, tj1 * 32);
    for (int e = tid; e < 3200; e += NT) {                // image pad cols 200..231 = 0
        int row = e >> 4, pc = e & 15;
        *(unsigned*)(LDS + row * 464 + 400 + pc * 4) = 0;
    }
    __syncthreads();                                      // stats dead from here on

    // ---- row sums -> dinv (LDS only) + deferred YT pad zeroing ----
    if (tid < 200) {
        float s = 1.f;                                     // the +I
#pragma unroll 4
        for (int e2 = 0; e2 < 29; ++e2) {
            short8 v = *(const short8*)(LDS + tid * 464 + e2 * 16);
#pragma unroll
            for (int j = 0; j < 8; ++j) s += bf2f((unsigned short)v[j]);
        }
        *(float*)(LDS + LS_DINV + tid * 4) = rsqrtf(s);
    }
    for (int e = tid; e < 64 * 16; e += NT) {             // YT pads = 0 (stats now dead)
        int l = e >> 4, d = e & 15;
        *(unsigned*)(LDS + LS_YT + l * 464 + 400 + d * 4) = 0;
    }
    __syncthreads();

    // ================= GCN (proven structure; rt step = 16 waves) =================
    // ---- G1: t1 = A @ W1; y = dinv*t1 -> YT (bf16 [l][j]) ----
    for (int rt = wid; rt < 13; rt += 16) {
        int row = rt * 16 + l15; int rowc = (row < 200) ? row : 199;
        f32x4 ac[4] = {};
        gemm4(LDS, rowc * 464 + hi16 * 16,
              LS_BUF2 + (l15) * 464 + hi16 * 16,
              LS_BUF2 + (16 + l15) * 464 + hi16 * 16,
              LS_BUF2 + (32 + l15) * 464 + hi16 * 16,
              LS_BUF2 + (48 + l15) * 464 + hi16 * 16, 7, ac);
        int j0 = rt * 16 + hi16 * 4;
        if (j0 < 200) {
            float d0v = *(const float*)(LDS + LS_DINV + (j0 + 0) * 4);
            float d1v = *(const float*)(LDS + LS_DINV + (j0 + 1) * 4);
            float d2v = *(const float*)(LDS + LS_DINV + (j0 + 2) * 4);
            float d3v = *(const float*)(LDS + LS_DINV + (j0 + 3) * 4);
#pragma unroll
            for (int ct = 0; ct < 4; ++ct) {
                int c = ct * 16 + l15;
                unsigned u0 = bf16r(d0v * ac[ct][0]) | (bf16r(d1v * ac[ct][1]) << 16);
                unsigned u1 = bf16r(d2v * ac[ct][2]) | (bf16r(d3v * ac[ct][3]) << 16);
                uint2 uu; uu.x = u0; uu.y = u1;
                *(uint2*)(LDS + LS_YT + c * 464 + j0 * 2) = uu;
            }
        }
    }
    __syncthreads();

    // ---- G2: z = A @ y; h = relu(dinv_i*(z + y_i) + b1) -> BUF2 ----
    for (int rt = wid; rt < 13; rt += 16) {
        int row = rt * 16 + l15; int rowc = (row < 200) ? row : 199;
        f32x4 ac[4] = {};
        gemm4(LDS, rowc * 464 + hi16 * 16,
              LS_YT + (l15) * 464 + hi16 * 16,
              LS_YT + (16 + l15) * 464 + hi16 * 16,
              LS_YT + (32 + l15) * 464 + hi16 * 16,
              LS_YT + (48 + l15) * 464 + hi16 * 16, 7, ac);
#pragma unroll
        for (int ct = 0; ct < 4; ++ct) {
            int c = ct * 16 + l15;
            float bias = *(const float*)(LDS + LS_B1 + c * 4);
#pragma unroll
            for (int r = 0; r < 4; ++r) {
                int i = rt * 16 + hi16 * 4 + r;
                if (i < 200) {
                    float dv = *(const float*)(LDS + LS_DINV + i * 4);
                    float yi = bf2f(*(const unsigned short*)(LDS + LS_YT + c * 464 + i * 2));
                    float v = dv * (ac[ct][r] + yi) + bias;
                    *(unsigned short*)(LDS + LS_BUF2 + i * 144 + c * 2) =
                        (unsigned short)bf16r(fmaxf(v, 0.f));
                }
            }
        }
    }
    __syncthreads();

    // ---- G3: t2 = h @ W2; y2 = dinv*t2 -> YT ----
    for (int rt = wid; rt < 13; rt += 16) {
        int row = rt * 16 + l15; int rowc = (row < 200) ? row : 199;
        f32x4 ac[4] = {};
        gemm4(LDS, LS_BUF2 + rowc * 144 + hi16 * 16,
              LS_W2T + (l15) * 144 + hi16 * 16,
              LS_W2T + (16 + l15) * 144 + hi16 * 16,
              LS_W2T + (32 + l15) * 144 + hi16 * 16,
              LS_W2T + (48 + l15) * 144 + hi16 * 16, 2, ac);
        int j0 = rt * 16 + hi16 * 4;
        if (j0 < 200) {
            float d0v = *(const float*)(LDS + LS_DINV + (j0 + 0) * 4);
            float d1v = *(const float*)(LDS + LS_DINV + (j0 + 1) * 4);
            float d2v = *(const float*)(LDS + LS_DINV + (j0 + 2) * 4);
            float d3v = *(const float*)(LDS + LS_DINV + (j0 + 3) * 4);
#pragma unroll
            for (int ct = 0; ct < 4; ++ct) {
                int c = ct * 16 + l15;
                unsigned u0 = bf16r(d0v * ac[ct][0]) | (bf16r(d1v * ac[ct][1]) << 16);
                unsigned u1 = bf16r(d2v * ac[ct][2]) | (bf16r(d3v * ac[ct][3]) << 16);
                uint2 uu; uu.x = u0; uu.y = u1;
                *(uint2*)(LDS + LS_YT + c * 464 + j0 * 2) = uu;
            }
        }
    }
    __syncthreads();

    // ---- G4: z2 = A @ y2; out = relu(dinv_i*(z2 + y2_i) + b2) ----
    for (int rt = wid; rt < 13; rt += 16) {
        int row = rt * 16 + l15; int rowc = (row < 200) ? row : 199;
        f32x4 ac[4] = {};
        gemm4(LDS, rowc * 464 + hi16 * 16,
              LS_YT + (l15) * 464 + hi16 * 16,
              LS_YT + (16 + l15) * 464 + hi16 * 16,
              LS_YT + (32 + l15) * 464 + hi16 * 16,
              LS_YT + (48 + l15) * 464 + hi16 * 16, 7, ac);
#pragma unroll
        for (int ct = 0; ct < 4; ++ct) {
            int c = ct * 16 + l15;
            float bias = *(const float*)(LDS + LS_B2 + c * 4);
#pragma unroll
            for (int r = 0; r < 4; ++r) {
                int i = rt * 16 + hi16 * 4 + r;
                if (i < 200) {
                    float dv = *(const float*)(LDS + LS_DINV + i * 4);
                    float yi = bf2f(*(const unsigned short*)(LDS + LS_YT + c * 464 + i * 2));
                    float v = dv * (ac[ct][r] + yi) + bias;
                    out[((size_t)b * N + i) * H + c] = fmaxf(v, 0.f);
                }
            }
        }
    }
}

extern "C" void kernel_launch(void* const* d_in, const int* in_sizes, int n_in,
                              void* d_out, int out_size, void* d_ws, size_t ws_size,
                              hipStream_t stream) {
    const float* data = (const float*)d_in[0];
    const float* W1   = (const float*)d_in[1];
    const float* b1   = (const float*)d_in[2];
    const float* W2   = (const float*)d_in[3];
    const float* b2   = (const float*)d_in[4];
    float* out = (float*)d_out;

    hipLaunchKernelGGL(k_fused, dim3(B), dim3(NT), 0, stream, data, W1, b1, W2, b2, out);
}

// Round 11
// 57.838 us; speedup vs baseline: 1.8348x; 1.1622x over previous
//
#include <hip/hip_runtime.h>
#include <math.h>

#define B 512
#define T 256
#define N 200
#define H 64
#define TN (T*N)     // 51200
#define NT 1024      // 16 waves -> 4 waves/SIMD

#define ARS 232              // A image row stride in bf16 (464 B)
#define XTRS 80              // Xt row stride bytes (32 bf16 + 16B pad; 5 slots, odd -> skew)

// ---- fused-kernel LDS map (byte offsets), sequenced by liveness (proven r9/r10) ----
#define LS_S(i)  (25600*(i))            // 4 x [32 t][200 n] f32 staging ring
#define LS_XT(i) (102400 + 16000*(i))   // 2 x [200 n][32 t] bf16 stride 80
#define LS_MUS   92800                  // 800 f32 mu partials (4 sets of 200)
#define LS_VARA  96000                  // 200 f32 raw diag
#define LS_MUA   96800
#define LS_RSA   97600                  // ..98400
#define LS_YT    92800                  // 64 x 464 B  (pads zeroed AFTER stats die)
#define LS_BUF2  122496                 // 64 x 464 B  (W1T, then h; overlaps dead Xt1)
#define LS_W2T   152192                 // 64 x 144 B
#define LS_DINV  161408                 // 200 f32
#define LS_B1    162208
#define LS_B2    162464
#define LS_SZ    162720

typedef short short8 __attribute__((ext_vector_type(8)));
typedef float f32x16 __attribute__((ext_vector_type(16)));

__device__ __forceinline__ unsigned bf16r(float x) {
    unsigned u = __float_as_uint(x);
    return (u + 0x7fffu + ((u >> 16) & 1u)) >> 16;   // round-to-nearest-even
}
__device__ __forceinline__ float bf2f(unsigned short u) {
    return __uint_as_float(((unsigned)u) << 16);
}
__device__ __forceinline__ void gll16(const void* g, void* l) {
    __builtin_amdgcn_global_load_lds(
        (const __attribute__((address_space(1))) unsigned*)g,
        (__attribute__((address_space(3))) unsigned*)l, 16, 0, 0);
}

// counted waitcnt: loads stay in flight ACROSS the raw barrier (T3+T4)
#define WAITV(n) asm volatile("s_waitcnt vmcnt(" #n ") lgkmcnt(0)" ::: "memory")

__global__ __launch_bounds__(NT) void k_fused(const float* __restrict__ data,
                                              const float* __restrict__ W1,
                                              const float* __restrict__ b1f,
                                              const float* __restrict__ W2,
                                              const float* __restrict__ b2f,
                                              float* __restrict__ out) {
    __shared__ __align__(16) unsigned char LDS[LS_SZ];
    const int tid  = threadIdx.x;
    const int b    = blockIdx.x;
    const int lane = tid & 63;
    const int wid  = tid >> 6;          // 0..15
    const int l31  = lane & 31;
    const int hi32 = lane >> 5;
    const float4* db4 = (const float4*)(data + (size_t)b * TN);

    f32x16 acc0 = {}, acc1 = {};
    float mu0 = 0.f;
    const int n0 = tid % 200, q0 = tid / 200;   // transpose unit (tid<800 only)

    // ---- corr tile assignment: 28 upper-tri tiles = 12 A-sharing pairs + 4 singles ----
    // pair wave: tiles (ti,tj0),(ti,tj0+1) share the A-panel fragment (1 A read feeds 2 MFMAs)
    int ti, tj0_; bool dual;
    if      (wid == 0)  { ti = 0; tj0_ = 0; dual = true;  }
    else if (wid == 1)  { ti = 0; tj0_ = 2; dual = true;  }
    else if (wid == 2)  { ti = 0; tj0_ = 4; dual = true;  }
    else if (wid == 3)  { ti = 1; tj0_ = 1; dual = true;  }
    else if (wid == 4)  { ti = 1; tj0_ = 3; dual = true;  }
    else if (wid == 5)  { ti = 1; tj0_ = 5; dual = true;  }
    else if (wid == 6)  { ti = 2; tj0_ = 2; dual = true;  }
    else if (wid == 7)  { ti = 2; tj0_ = 4; dual = true;  }
    else if (wid == 8)  { ti = 3; tj0_ = 3; dual = true;  }
    else if (wid == 9)  { ti = 3; tj0_ = 5; dual = true;  }
    else if (wid == 10) { ti = 4; tj0_ = 4; dual = true;  }
    else if (wid == 11) { ti = 5; tj0_ = 5; dual = true;  }
    else if (wid == 12) { ti = 0; tj0_ = 6; dual = false; }
    else if (wid == 13) { ti = 2; tj0_ = 6; dual = false; }
    else if (wid == 14) { ti = 4; tj0_ = 6; dual = false; }
    else                { ti = 6; tj0_ = 6; dual = false; }
    const int tj1_ = tj0_ + 1;
    const bool diag0 = (ti == tj0_);
    int arow = ti * 32 + l31;   if (arow > 199) arow = 199;
    int bc0  = tj0_ * 32 + l31; if (bc0 > 199)  bc0 = 199;
    int bc1  = tj1_ * 32 + l31; if (bc1 > 199)  bc1 = 199;

    // stage chunk cc into 4-deep ring: 25 x 1KB gll16; waves 0-11 issue 2, wave 12 one
    auto stage = [&](int cc) {
        const float4* src = db4 + cc * 1600;
        unsigned char* dst = LDS + LS_S(cc & 3);
#pragma unroll
        for (int i = 0; i < 2; ++i) {
            int p = (wid << 1) + i;
            if (p < 25) {
                int idx = (p << 6) + lane;
                gll16(src + idx, dst + idx * 16);
            }
        }
    };
    // transpose chunk c: S[c&3] f32 [32t][200n] -> Xt[c&1] bf16 [200n][32t]
    auto transpose = [&](int c) {
        if (tid < 800) {
            const float* s0 = (const float*)(LDS + LS_S(c & 3)) + (q0 * 8) * 200 + n0;
            unsigned u[4]; float a = 0.f;
#pragma unroll
            for (int j = 0; j < 4; ++j) {
                unsigned b0 = bf16r(s0[(2 * j) * 200]);
                unsigned b1 = bf16r(s0[(2 * j + 1) * 200]);
                a += bf2f((unsigned short)b0) + bf2f((unsigned short)b1);
                u[j] = b0 | (b1 << 16);
            }
            mu0 += a;
            uint4 pk; pk.x = u[0]; pk.y = u[1]; pk.z = u[2]; pk.w = u[3];
            *(uint4*)(LDS + LS_XT(c & 1) + n0 * XTRS + q0 * 16) = pk;
        }
    };
    auto domfma = [&](int cp) {
        const unsigned char* Xp = LDS + LS_XT(cp & 1);
#pragma unroll
        for (int kc = 0; kc < 2; ++kc) {
            int kb = kc * 32 + hi32 * 16;
            short8 a = *(const short8*)(Xp + arow * XTRS + kb);
            short8 b0 = diag0 ? a : *(const short8*)(Xp + bc0 * XTRS + kb);
            acc0 = __builtin_amdgcn_mfma_f32_32x32x16_bf16(a, b0, acc0, 0, 0, 0);
            if (dual) {
                short8 b1 = *(const short8*)(Xp + bc1 * XTRS + kb);
                acc1 = __builtin_amdgcn_mfma_f32_32x32x16_bf16(a, b1, acc1, 0, 0, 0);
            }
        }
    };

    // ---- corr K-loop: 2-deep prefetch, counted vmcnt, raw barriers (proven r9/r10) ----
    stage(0); stage(1);
#pragma unroll
    for (int c = 0; c < 8; ++c) {
        if (c < 6) stage(c + 2);
        if (wid < 12)       { if (c < 6) WAITV(4); else if (c == 6) WAITV(2); else WAITV(0); }
        else if (wid == 12) { if (c < 6) WAITV(2); else if (c == 6) WAITV(1); else WAITV(0); }
        else                { WAITV(0); }
        __builtin_amdgcn_sched_barrier(0);
        __builtin_amdgcn_s_barrier();        // S[c] + Xt[c-1] now valid for all waves
        __builtin_amdgcn_sched_barrier(0);
        if (c > 0) domfma(c - 1);
        transpose(c);
    }
    asm volatile("s_waitcnt lgkmcnt(0)" ::: "memory");
    __builtin_amdgcn_s_barrier();            // publish Xt[7]
    __builtin_amdgcn_sched_barrier(0);
    domfma(7);
    asm volatile("s_waitcnt lgkmcnt(0)" ::: "memory");
    __builtin_amdgcn_s_barrier();            // Xt dead -> BUF2 (overlaps Xt1) writable
    __builtin_amdgcn_sched_barrier(0);

    // ---- weight staging + mu partials + raw diag (stats region disjoint from writes) ----
    for (int e = tid; e < N * H; e += NT) {               // W1^T -> BUF2
        int k = e >> 6, l = e & 63;
        *(unsigned short*)(LDS + LS_BUF2 + l * 464 + k * 2) = (unsigned short)bf16r(W1[e]);
    }
    for (int e = tid; e < 64 * 16; e += NT) {             // W1T pads = 0
        int l = e >> 4, d = e & 15;
        *(unsigned*)(LDS + LS_BUF2 + l * 464 + 400 + d * 4) = 0;
    }
    for (int e = tid; e < H * H; e += NT) {               // W2^T
        int k = e >> 6, l = e & 63;
        *(unsigned short*)(LDS + LS_W2T + l * 144 + k * 2) = (unsigned short)bf16r(W2[e]);
    }
    if (tid < 64) *(float*)(LDS + LS_B1 + tid * 4) = b1f[tid];
    else if (tid < 128) *(float*)(LDS + LS_B2 + (tid - 64) * 4) = b2f[tid - 64];

    if (tid < 800) *(float*)(LDS + LS_MUS + tid * 4) = mu0;   // slot q0*200+n0 == tid
    if (diag0) {
#pragma unroll
        for (int r = 0; r < 16; ++r) {
            int rowin = (r & 3) + 8 * (r >> 2) + 4 * hi32;
            int n = ti * 32 + rowin;
            if (l31 == rowin && n < 200)
                *(float*)(LDS + LS_VARA + n * 4) = acc0[r];   // S_nn
        }
    }
    __syncthreads();

    // ---- per-node mu, rs ----
    if (tid < 200) {
        float s = *(const float*)(LDS + LS_MUS + tid * 4)
                + *(const float*)(LDS + LS_MUS + 800 + tid * 4)
                + *(const float*)(LDS + LS_MUS + 1600 + tid * 4)
                + *(const float*)(LDS + LS_MUS + 2400 + tid * 4);
        float mu = s * (1.f / 256.f);
        float var = *(const float*)(LDS + LS_VARA + tid * 4) - 256.f * mu * mu;
        *(float*)(LDS + LS_MUA + tid * 4) = mu;
        *(float*)(LDS + LS_RSA + tid * 4) = (var > 0.f) ? rsqrtf(var) : 0.f;
    }
    __syncthreads();

    // ---- epilogue: |corr| -> image [200][232] bf16 (upper tile + mirror) + pads ----
    unsigned short* A16 = (unsigned short*)LDS;
    auto epi = [&](const f32x16& ac, int ib, int jb) {
        int col = jb + l31;
        if (col < 200) {
            float muc = *(const float*)(LDS + LS_MUA + col * 4);
            float rsc = *(const float*)(LDS + LS_RSA + col * 4);
#pragma unroll
            for (int r = 0; r < 16; ++r) {
                int row = ib + (r & 3) + 8 * (r >> 2) + 4 * hi32;
                if (row < 200) {
                    float mur = *(const float*)(LDS + LS_MUA + row * 4);
                    float rsr = *(const float*)(LDS + LS_RSA + row * 4);
                    float corr = (ac[r] - 256.f * mur * muc) * (rsr * rsc);
                    unsigned short bv = (unsigned short)bf16r(fabsf(corr));
                    A16[row * ARS + col] = bv;
                    if (ib != jb) A16[col * ARS + row] = bv;   // symmetric mirror
                }
            }
        }
    };
    epi(acc0, ti * 32, tj0_ * 32);
    if (dual) epi(acc1, ti * 32, tj1_ * 32);
    for (int e = tid; e < 3200; e += NT) {                // image pad cols 200..231 = 0
        int row = e >> 4, pc = e & 15;
        *(unsigned*)(LDS + row * 464 + 400 + pc * 4) = 0;
    }
    __syncthreads();                                      // stats dead from here on

    // ---- row sums -> dinv (LDS only) + deferred YT pad zeroing ----
    if (tid < 200) {
        float s = 1.f;                                     // the +I
#pragma unroll 4
        for (int e2 = 0; e2 < 29; ++e2) {
            short8 v = *(const short8*)(LDS + tid * 464 + e2 * 16);
#pragma unroll
            for (int j = 0; j < 8; ++j) s += bf2f((unsigned short)v[j]);
        }
        *(float*)(LDS + LS_DINV + tid * 4) = rsqrtf(s);
    }
    for (int e = tid; e < 64 * 16; e += NT) {             // YT pads = 0 (stats now dead)
        int l = e >> 4, d = e & 15;
        *(unsigned*)(LDS + LS_YT + l * 464 + 400 + d * 4) = 0;
    }
    __syncthreads();

    // ================= GCN: 32x32x16 MFMA, 14 units (7 row-tiles x 2 col-tiles) ========
    // C/D layout (proven): col = l31, row_in_tile = (r&3) + 8*(r>>2) + 4*hi32.
    // r-group g (r=4g..4g+3) -> 4 CONSECUTIVE rows j0..j0+3, j0 = tr*32 + 8g + 4*hi32.
    // K = 208 = 13 chunks of 16 (cols 200..207 are zero pads). G3: K = 64 = 4 chunks.
    const int tr = wid >> 1, tc = wid & 1;                // unit (wid<14)
    const int gc = tc * 32 + l31;                         // output hidden channel
    int grow = tr * 32 + l31; if (grow > 199) grow = 199; // A-frag row (clamped dup)

    // ---- G1: t1 = A @ W1; y = dinv*t1 -> YT[c][j] ----
    if (wid < 14) {
        f32x16 ac = {};
#pragma unroll
        for (int ch = 0; ch < 13; ++ch) {
            int kb = ch * 32 + hi32 * 16;
            short8 av = *(const short8*)(LDS + grow * 464 + kb);
            short8 bv = *(const short8*)(LDS + LS_BUF2 + gc * 464 + kb);
            ac = __builtin_amdgcn_mfma_f32_32x32x16_bf16(av, bv, ac, 0, 0, 0);
        }
#pragma unroll
        for (int g = 0; g < 4; ++g) {
            int j0 = tr * 32 + 8 * g + 4 * hi32;
            if (j0 < 200) {
                float4 dv4 = *(const float4*)(LDS + LS_DINV + j0 * 4);
                uint2 uu;
                uu.x = bf16r(dv4.x * ac[4 * g + 0]) | (bf16r(dv4.y * ac[4 * g + 1]) << 16);
                uu.y = bf16r(dv4.z * ac[4 * g + 2]) | (bf16r(dv4.w * ac[4 * g + 3]) << 16);
                *(uint2*)(LDS + LS_YT + gc * 464 + j0 * 2) = uu;
            }
        }
    }
    __syncthreads();

    // ---- G2: z = A @ y; h = relu(dinv_i*(z + y_i) + b1) -> BUF2[i][c] ----
    if (wid < 14) {
        f32x16 ac = {};
#pragma unroll
        for (int ch = 0; ch < 13; ++ch) {
            int kb = ch * 32 + hi32 * 16;
            short8 av = *(const short8*)(LDS + grow * 464 + kb);
            short8 bv = *(const short8*)(LDS + LS_YT + gc * 464 + kb);
            ac = __builtin_amdgcn_mfma_f32_32x32x16_bf16(av, bv, ac, 0, 0, 0);
        }
        float bias = *(const float*)(LDS + LS_B1 + gc * 4);
#pragma unroll
        for (int g = 0; g < 4; ++g) {
            int i0 = tr * 32 + 8 * g + 4 * hi32;
            if (i0 < 200) {
                float4 dv4 = *(const float4*)(LDS + LS_DINV + i0 * 4);
                uint2 yv = *(const uint2*)(LDS + LS_YT + gc * 464 + i0 * 2);
                float y0 = bf2f((unsigned short)(yv.x & 0xffff));
                float y1 = bf2f((unsigned short)(yv.x >> 16));
                float y2 = bf2f((unsigned short)(yv.y & 0xffff));
                float y3 = bf2f((unsigned short)(yv.y >> 16));
                float v0 = fmaxf(dv4.x * (ac[4 * g + 0] + y0) + bias, 0.f);
                float v1 = fmaxf(dv4.y * (ac[4 * g + 1] + y1) + bias, 0.f);
                float v2 = fmaxf(dv4.z * (ac[4 * g + 2] + y2) + bias, 0.f);
                float v3 = fmaxf(dv4.w * (ac[4 * g + 3] + y3) + bias, 0.f);
                *(unsigned short*)(LDS + LS_BUF2 + (i0 + 0) * 144 + gc * 2) = (unsigned short)bf16r(v0);
                *(unsigned short*)(LDS + LS_BUF2 + (i0 + 1) * 144 + gc * 2) = (unsigned short)bf16r(v1);
                *(unsigned short*)(LDS + LS_BUF2 + (i0 + 2) * 144 + gc * 2) = (unsigned short)bf16r(v2);
                *(unsigned short*)(LDS + LS_BUF2 + (i0 + 3) * 144 + gc * 2) = (unsigned short)bf16r(v3);
            }
        }
    }
    __syncthreads();

    // ---- G3: t2 = h @ W2; y2 = dinv*t2 -> YT[c][j] (K = 64 = 4 chunks) ----
    if (wid < 14) {
        f32x16 ac = {};
#pragma unroll
        for (int ch = 0; ch < 4; ++ch) {
            int kb = ch * 32 + hi32 * 16;
            short8 av = *(const short8*)(LDS + LS_BUF2 + grow * 144 + kb);
            short8 bv = *(const short8*)(LDS + LS_W2T + gc * 144 + kb);
            ac = __builtin_amdgcn_mfma_f32_32x32x16_bf16(av, bv, ac, 0, 0, 0);
        }
#pragma unroll
        for (int g = 0; g < 4; ++g) {
            int j0 = tr * 32 + 8 * g + 4 * hi32;
            if (j0 < 200) {
                float4 dv4 = *(const float4*)(LDS + LS_DINV + j0 * 4);
                uint2 uu;
                uu.x = bf16r(dv4.x * ac[4 * g + 0]) | (bf16r(dv4.y * ac[4 * g + 1]) << 16);
                uu.y = bf16r(dv4.z * ac[4 * g + 2]) | (bf16r(dv4.w * ac[4 * g + 3]) << 16);
                *(uint2*)(LDS + LS_YT + gc * 464 + j0 * 2) = uu;
            }
        }
    }
    __syncthreads();

    // ---- G4: z2 = A @ y2; out = relu(dinv_i*(z2 + y2_i) + b2) ----
    if (wid < 14) {
        f32x16 ac = {};
#pragma unroll
        for (int ch = 0; ch < 13; ++ch) {
            int kb = ch * 32 + hi32 * 16;
            short8 av = *(const short8*)(LDS + grow * 464 + kb);
            short8 bv = *(const short8*)(LDS + LS_YT + gc * 464 + kb);
            ac = __builtin_amdgcn_mfma_f32_32x32x16_bf16(av, bv, ac, 0, 0, 0);
        }
        float bias = *(const float*)(LDS + LS_B2 + gc * 4);
#pragma unroll
        for (int g = 0; g < 4; ++g) {
            int i0 = tr * 32 + 8 * g + 4 * hi32;
            if (i0 < 200) {
                float4 dv4 = *(const float4*)(LDS + LS_DINV + i0 * 4);
                uint2 yv = *(const uint2*)(LDS + LS_YT + gc * 464 + i0 * 2);
                float y0 = bf2f((unsigned short)(yv.x & 0xffff));
                float y1 = bf2f((unsigned short)(yv.x >> 16));
                float y2 = bf2f((unsigned short)(yv.y & 0xffff));
                float y3 = bf2f((unsigned short)(yv.y >> 16));
                float* ob = out + ((size_t)b * N + i0) * H + gc;
                ob[0 * H] = fmaxf(dv4.x * (ac[4 * g + 0] + y0) + bias, 0.f);
                ob[1 * H] = fmaxf(dv4.y * (ac[4 * g + 1] + y1) + bias, 0.f);
                ob[2 * H] = fmaxf(dv4.z * (ac[4 * g + 2] + y2) + bias, 0.f);
                ob[3 * H] = fmaxf(dv4.w * (ac[4 * g + 3] + y3) + bias, 0.f);
            }
        }
    }
}

extern "C" void kernel_launch(void* const* d_in, const int* in_sizes, int n_in,
                              void* d_out, int out_size, void* d_ws, size_t ws_size,
                              hipStream_t stream) {
    const float* data = (const float*)d_in[0];
    const float* W1   = (const float*)d_in[1];
    const float* b1   = (const float*)d_in[2];
    const float* W2   = (const float*)d_in[3];
    const float* b2   = (const float*)d_in[4];
    float* out = (float*)d_out;

    hipLaunchKernelGGL(k_fused, dim3(B), dim3(NT), 0, stream, data, W1, b1, W2, b2, out);
}

// Round 12
// 57.499 us; speedup vs baseline: 1.8456x; 1.0059x over previous
//
#include <hip/hip_runtime.h>
#include <math.h>

#define B 512
#define T 256
#define N 200
#define H 64
#define TN (T*N)     // 51200
#define NT 1024      // 16 waves -> 4 waves/SIMD

#define ARS 232              // A image row stride in bf16 (464 B)
#define XTRS 80              // Xt row stride bytes (32 bf16 + 16B pad; 5 slots, odd -> skew)

// ---- fused-kernel LDS map (byte offsets), sequenced by liveness (proven r9-r11) ----
#define LS_S(i)  (25600*(i))            // 4 x [32 t][200 n] f32 staging ring
#define LS_XT(i) (102400 + 16000*(i))   // 2 x [200 n][32 t] bf16 stride 80
#define LS_MUS   92800                  // 800 f32 mu partials (4 sets of 200)
#define LS_VARA  96000                  // 200 f32 raw diag
#define LS_MUA   96800
#define LS_RSA   97600                  // ..98400
#define LS_YT    92800                  // 64 x 464 B  (pads zeroed AFTER stats die)
#define LS_BUF2  122496                 // 64 x 464 B  (W1T, then h; overlaps dead Xt1)
#define LS_W2T   152192                 // 64 x 144 B
#define LS_DINV  161408                 // 200 f32
#define LS_B1    162208
#define LS_B2    162464
#define LS_SZ    162720

typedef short short8 __attribute__((ext_vector_type(8)));
typedef float f32x16 __attribute__((ext_vector_type(16)));

__device__ __forceinline__ unsigned bf16r(float x) {
    unsigned u = __float_as_uint(x);
    return (u + 0x7fffu + ((u >> 16) & 1u)) >> 16;   // round-to-nearest-even
}
__device__ __forceinline__ float bf2f(unsigned short u) {
    return __uint_as_float(((unsigned)u) << 16);
}
__device__ __forceinline__ void gll16(const void* g, void* l) {
    __builtin_amdgcn_global_load_lds(
        (const __attribute__((address_space(1))) unsigned*)g,
        (__attribute__((address_space(3))) unsigned*)l, 16, 0, 0);
}

// counted waitcnt: loads stay in flight ACROSS the raw barrier (T3+T4)
#define WAITV(n) asm volatile("s_waitcnt vmcnt(" #n ") lgkmcnt(0)" ::: "memory")

__global__ __launch_bounds__(NT) void k_fused(const float* __restrict__ data,
                                              const float* __restrict__ W1,
                                              const float* __restrict__ b1f,
                                              const float* __restrict__ W2,
                                              const float* __restrict__ b2f,
                                              float* __restrict__ out) {
    __shared__ __align__(16) unsigned char LDS[LS_SZ];
    const int tid  = threadIdx.x;
    const int b    = blockIdx.x;
    const int lane = tid & 63;
    const int wid  = tid >> 6;          // 0..15
    const int l31  = lane & 31;
    const int hi32 = lane >> 5;
    const float4* db4 = (const float4*)(data + (size_t)b * TN);

    f32x16 acc0 = {}, acc1 = {};
    float mu0 = 0.f;
    const int n0 = tid % 200, q0 = tid / 200;   // transpose unit (tid<800 only)

    // ---- corr tile assignment: 28 upper-tri tiles = 12 A-sharing pairs + 4 singles ----
    int ti, tj0_; bool dual;
    if      (wid == 0)  { ti = 0; tj0_ = 0; dual = true;  }
    else if (wid == 1)  { ti = 0; tj0_ = 2; dual = true;  }
    else if (wid == 2)  { ti = 0; tj0_ = 4; dual = true;  }
    else if (wid == 3)  { ti = 1; tj0_ = 1; dual = true;  }
    else if (wid == 4)  { ti = 1; tj0_ = 3; dual = true;  }
    else if (wid == 5)  { ti = 1; tj0_ = 5; dual = true;  }
    else if (wid == 6)  { ti = 2; tj0_ = 2; dual = true;  }
    else if (wid == 7)  { ti = 2; tj0_ = 4; dual = true;  }
    else if (wid == 8)  { ti = 3; tj0_ = 3; dual = true;  }
    else if (wid == 9)  { ti = 3; tj0_ = 5; dual = true;  }
    else if (wid == 10) { ti = 4; tj0_ = 4; dual = true;  }
    else if (wid == 11) { ti = 5; tj0_ = 5; dual = true;  }
    else if (wid == 12) { ti = 0; tj0_ = 6; dual = false; }
    else if (wid == 13) { ti = 2; tj0_ = 6; dual = false; }
    else if (wid == 14) { ti = 4; tj0_ = 6; dual = false; }
    else                { ti = 6; tj0_ = 6; dual = false; }
    const int tj1_ = tj0_ + 1;
    const bool diag0 = (ti == tj0_);
    int arow = ti * 32 + l31;   if (arow > 199) arow = 199;
    int bc0  = tj0_ * 32 + l31; if (bc0 > 199)  bc0 = 199;
    int bc1  = tj1_ * 32 + l31; if (bc1 > 199)  bc1 = 199;

    auto stage = [&](int cc) {
        const float4* src = db4 + cc * 1600;
        unsigned char* dst = LDS + LS_S(cc & 3);
#pragma unroll
        for (int i = 0; i < 2; ++i) {
            int p = (wid << 1) + i;
            if (p < 25) {
                int idx = (p << 6) + lane;
                gll16(src + idx, dst + idx * 16);
            }
        }
    };
    auto transpose = [&](int c) {
        if (tid < 800) {
            const float* s0 = (const float*)(LDS + LS_S(c & 3)) + (q0 * 8) * 200 + n0;
            unsigned u[4]; float a = 0.f;
#pragma unroll
            for (int j = 0; j < 4; ++j) {
                unsigned b0 = bf16r(s0[(2 * j) * 200]);
                unsigned b1 = bf16r(s0[(2 * j + 1) * 200]);
                a += bf2f((unsigned short)b0) + bf2f((unsigned short)b1);
                u[j] = b0 | (b1 << 16);
            }
            mu0 += a;
            uint4 pk; pk.x = u[0]; pk.y = u[1]; pk.z = u[2]; pk.w = u[3];
            *(uint4*)(LDS + LS_XT(c & 1) + n0 * XTRS + q0 * 16) = pk;
        }
    };
    auto domfma = [&](int cp) {
        const unsigned char* Xp = LDS + LS_XT(cp & 1);
#pragma unroll
        for (int kc = 0; kc < 2; ++kc) {
            int kb = kc * 32 + hi32 * 16;
            short8 a = *(const short8*)(Xp + arow * XTRS + kb);
            short8 b0 = diag0 ? a : *(const short8*)(Xp + bc0 * XTRS + kb);
            acc0 = __builtin_amdgcn_mfma_f32_32x32x16_bf16(a, b0, acc0, 0, 0, 0);
            if (dual) {
                short8 b1 = *(const short8*)(Xp + bc1 * XTRS + kb);
                acc1 = __builtin_amdgcn_mfma_f32_32x32x16_bf16(a, b1, acc1, 0, 0, 0);
            }
        }
    };

    // ---- corr K-loop: 2-deep prefetch, counted vmcnt, raw barriers (proven) ----
    stage(0); stage(1);
#pragma unroll
    for (int c = 0; c < 8; ++c) {
        if (c < 6) stage(c + 2);
        if (wid < 12)       { if (c < 6) WAITV(4); else if (c == 6) WAITV(2); else WAITV(0); }
        else if (wid == 12) { if (c < 6) WAITV(2); else if (c == 6) WAITV(1); else WAITV(0); }
        else                { WAITV(0); }
        __builtin_amdgcn_sched_barrier(0);
        __builtin_amdgcn_s_barrier();        // S[c] + Xt[c-1] now valid for all waves
        __builtin_amdgcn_sched_barrier(0);
        if (c > 0) domfma(c - 1);
        transpose(c);
    }
    asm volatile("s_waitcnt lgkmcnt(0)" ::: "memory");
    __builtin_amdgcn_s_barrier();            // publish Xt[7]
    __builtin_amdgcn_sched_barrier(0);
    domfma(7);
    asm volatile("s_waitcnt lgkmcnt(0)" ::: "memory");
    __builtin_amdgcn_s_barrier();            // Xt dead -> BUF2 (overlaps Xt1) writable
    __builtin_amdgcn_sched_barrier(0);

    // ---- weight staging + mu partials + raw diag (stats region disjoint from writes) ----
    for (int e = tid; e < N * H; e += NT) {               // W1^T -> BUF2
        int k = e >> 6, l = e & 63;
        *(unsigned short*)(LDS + LS_BUF2 + l * 464 + k * 2) = (unsigned short)bf16r(W1[e]);
    }
    for (int e = tid; e < 64 * 16; e += NT) {             // W1T pads = 0
        int l = e >> 4, d = e & 15;
        *(unsigned*)(LDS + LS_BUF2 + l * 464 + 400 + d * 4) = 0;
    }
    for (int e = tid; e < H * H; e += NT) {               // W2^T
        int k = e >> 6, l = e & 63;
        *(unsigned short*)(LDS + LS_W2T + l * 144 + k * 2) = (unsigned short)bf16r(W2[e]);
    }
    if (tid < 64) *(float*)(LDS + LS_B1 + tid * 4) = b1f[tid];
    else if (tid < 128) *(float*)(LDS + LS_B2 + (tid - 64) * 4) = b2f[tid - 64];

    if (tid < 800) *(float*)(LDS + LS_MUS + tid * 4) = mu0;   // slot q0*200+n0 == tid
    if (diag0) {
#pragma unroll
        for (int r = 0; r < 16; ++r) {
            int rowin = (r & 3) + 8 * (r >> 2) + 4 * hi32;
            int n = ti * 32 + rowin;
            if (l31 == rowin && n < 200)
                *(float*)(LDS + LS_VARA + n * 4) = acc0[r];   // S_nn
        }
    }
    __syncthreads();

    // ---- per-node mu, rs ----
    if (tid < 200) {
        float s = *(const float*)(LDS + LS_MUS + tid * 4)
                + *(const float*)(LDS + LS_MUS + 800 + tid * 4)
                + *(const float*)(LDS + LS_MUS + 1600 + tid * 4)
                + *(const float*)(LDS + LS_MUS + 2400 + tid * 4);
        float mu = s * (1.f / 256.f);
        float var = *(const float*)(LDS + LS_VARA + tid * 4) - 256.f * mu * mu;
        *(float*)(LDS + LS_MUA + tid * 4) = mu;
        *(float*)(LDS + LS_RSA + tid * 4) = (var > 0.f) ? rsqrtf(var) : 0.f;
    }
    __syncthreads();

    // ---- epilogue: |corr| -> image [200][232] bf16.
    // MFMA tile is bit-exact symmetric (same k-order both operands), so the value
    // for (row,col) may be written at [col][row]. The C-layout reg-quad (r=4g..4g+3)
    // is 4 CONSECUTIVE rows at one col -> packed uint2 write at the TRANSPOSED slot
    // [col][row..row+3] fills region (jb,ib) (and all of a diag tile). Off-diag
    // additionally scatters scalars at [row][col] for region (ib,jb).
    unsigned short* A16 = (unsigned short*)LDS;
    auto epi = [&](const f32x16& ac, int ib, int jb) {
        int col = jb + l31;
        if (col < 200) {
            float muc = *(const float*)(LDS + LS_MUA + col * 4);
            float rsc = *(const float*)(LDS + LS_RSA + col * 4);
            unsigned short cv[16];
#pragma unroll
            for (int g = 0; g < 4; ++g) {
                int rb = ib + 8 * g + 4 * hi32;           // quad base row (mult of 4)
                float4 mur4 = *(const float4*)(LDS + LS_MUA + rb * 4);  // may read junk
                float4 rsr4 = *(const float4*)(LDS + LS_RSA + rb * 4);  // (writes guarded)
                cv[4*g+0] = (unsigned short)bf16r(fabsf((ac[4*g+0] - 256.f * mur4.x * muc) * (rsr4.x * rsc)));
                cv[4*g+1] = (unsigned short)bf16r(fabsf((ac[4*g+1] - 256.f * mur4.y * muc) * (rsr4.y * rsc)));
                cv[4*g+2] = (unsigned short)bf16r(fabsf((ac[4*g+2] - 256.f * mur4.z * muc) * (rsr4.z * rsc)));
                cv[4*g+3] = (unsigned short)bf16r(fabsf((ac[4*g+3] - 256.f * mur4.w * muc) * (rsr4.w * rsc)));
                if (rb < 200) {                            // rb+3 <= 199 (rb mult of 4)
                    uint2 uu;
                    uu.x = (unsigned)cv[4*g+0] | ((unsigned)cv[4*g+1] << 16);
                    uu.y = (unsigned)cv[4*g+2] | ((unsigned)cv[4*g+3] << 16);
                    *(uint2*)(LDS + col * 464 + rb * 2) = uu;   // image[col][rb..rb+3]
                }
            }
            if (ib != jb) {                                // region (ib,jb): scalar
#pragma unroll
                for (int r = 0; r < 16; ++r) {
                    int row = ib + (r & 3) + 8 * (r >> 2) + 4 * hi32;
                    if (row < 200) A16[row * ARS + col] = cv[r];
                }
            }
        }
    };
    epi(acc0, ti * 32, tj0_ * 32);
    if (dual) epi(acc1, ti * 32, tj1_ * 32);
    for (int e = tid; e < 3200; e += NT) {                // image pad cols 200..231 = 0
        int row = e >> 4, pc = e & 15;
        *(unsigned*)(LDS + row * 464 + 400 + pc * 4) = 0;
    }
    __syncthreads();                                      // stats dead from here on

    // ---- row sums -> dinv (LDS only) + deferred YT pad zeroing ----
    if (tid < 200) {
        float s = 1.f;                                     // the +I
#pragma unroll 4
        for (int e2 = 0; e2 < 29; ++e2) {
            short8 v = *(const short8*)(LDS + tid * 464 + e2 * 16);
#pragma unroll
            for (int j = 0; j < 8; ++j) s += bf2f((unsigned short)v[j]);
        }
        *(float*)(LDS + LS_DINV + tid * 4) = rsqrtf(s);
    }
    for (int e = tid; e < 64 * 16; e += NT) {             // YT pads = 0 (stats now dead)
        int l = e >> 4, d = e & 15;
        *(unsigned*)(LDS + LS_YT + l * 464 + 400 + d * 4) = 0;
    }
    __syncthreads();

    // ============ GCN: 32x32x16 MFMA, 7 waves x (1 row-tile x BOTH col-tiles) ========
    // One A-fragment read feeds 2 MFMAs (col-pairing): reads 364->273 per GEMM.
    // C/D layout: col = l31, row_in_tile = (r&3) + 8*(r>>2) + 4*hi32; quad g -> 4
    // consecutive rows j0 = tr*32 + 8g + 4*hi32. K = 208 (13 ch; 200..207 zero pads).
    const int tr = wid;                                   // row-tile (wid<7)
    const int gc0 = l31, gc1 = 32 + l31;                  // the two output channels
    int grow = tr * 32 + l31; if (grow > 199) grow = 199; // A-frag row (clamped dup)

    // ---- G1: t1 = A @ W1; y = dinv*t1 -> YT[c][j] ----
    if (wid < 7) {
        f32x16 a0 = {}, a1 = {};
#pragma unroll
        for (int ch = 0; ch < 13; ++ch) {
            int kb = ch * 32 + hi32 * 16;
            short8 av = *(const short8*)(LDS + grow * 464 + kb);
            short8 bv0 = *(const short8*)(LDS + LS_BUF2 + gc0 * 464 + kb);
            short8 bv1 = *(const short8*)(LDS + LS_BUF2 + gc1 * 464 + kb);
            a0 = __builtin_amdgcn_mfma_f32_32x32x16_bf16(av, bv0, a0, 0, 0, 0);
            a1 = __builtin_amdgcn_mfma_f32_32x32x16_bf16(av, bv1, a1, 0, 0, 0);
        }
#pragma unroll
        for (int g = 0; g < 4; ++g) {
            int j0 = tr * 32 + 8 * g + 4 * hi32;
            if (j0 < 200) {
                float4 dv4 = *(const float4*)(LDS + LS_DINV + j0 * 4);
                uint2 u0, u1;
                u0.x = bf16r(dv4.x * a0[4*g+0]) | (bf16r(dv4.y * a0[4*g+1]) << 16);
                u0.y = bf16r(dv4.z * a0[4*g+2]) | (bf16r(dv4.w * a0[4*g+3]) << 16);
                u1.x = bf16r(dv4.x * a1[4*g+0]) | (bf16r(dv4.y * a1[4*g+1]) << 16);
                u1.y = bf16r(dv4.z * a1[4*g+2]) | (bf16r(dv4.w * a1[4*g+3]) << 16);
                *(uint2*)(LDS + LS_YT + gc0 * 464 + j0 * 2) = u0;
                *(uint2*)(LDS + LS_YT + gc1 * 464 + j0 * 2) = u1;
            }
        }
    }
    __syncthreads();

    // ---- G2: z = A @ y; h = relu(dinv_i*(z + y_i) + b1) -> BUF2[i][c] ----
    if (wid < 7) {
        f32x16 a0 = {}, a1 = {};
#pragma unroll
        for (int ch = 0; ch < 13; ++ch) {
            int kb = ch * 32 + hi32 * 16;
            short8 av = *(const short8*)(LDS + grow * 464 + kb);
            short8 bv0 = *(const short8*)(LDS + LS_YT + gc0 * 464 + kb);
            short8 bv1 = *(const short8*)(LDS + LS_YT + gc1 * 464 + kb);
            a0 = __builtin_amdgcn_mfma_f32_32x32x16_bf16(av, bv0, a0, 0, 0, 0);
            a1 = __builtin_amdgcn_mfma_f32_32x32x16_bf16(av, bv1, a1, 0, 0, 0);
        }
        float bias0 = *(const float*)(LDS + LS_B1 + gc0 * 4);
        float bias1 = *(const float*)(LDS + LS_B1 + gc1 * 4);
#pragma unroll
        for (int g = 0; g < 4; ++g) {
            int i0 = tr * 32 + 8 * g + 4 * hi32;
            if (i0 < 200) {
                float4 dv4 = *(const float4*)(LDS + LS_DINV + i0 * 4);
                uint2 yv0 = *(const uint2*)(LDS + LS_YT + gc0 * 464 + i0 * 2);
                uint2 yv1 = *(const uint2*)(LDS + LS_YT + gc1 * 464 + i0 * 2);
#pragma unroll
                for (int q = 0; q < 4; ++q) {
                    float dq = (q == 0) ? dv4.x : (q == 1) ? dv4.y : (q == 2) ? dv4.z : dv4.w;
                    unsigned yw0 = (q < 2) ? yv0.x : yv0.y;
                    unsigned yw1 = (q < 2) ? yv1.x : yv1.y;
                    float y0 = bf2f((unsigned short)((q & 1) ? (yw0 >> 16) : (yw0 & 0xffff)));
                    float y1 = bf2f((unsigned short)((q & 1) ? (yw1 >> 16) : (yw1 & 0xffff)));
                    float v0 = fmaxf(dq * (a0[4*g+q] + y0) + bias0, 0.f);
                    float v1 = fmaxf(dq * (a1[4*g+q] + y1) + bias1, 0.f);
                    *(unsigned short*)(LDS + LS_BUF2 + (i0 + q) * 144 + gc0 * 2) = (unsigned short)bf16r(v0);
                    *(unsigned short*)(LDS + LS_BUF2 + (i0 + q) * 144 + gc1 * 2) = (unsigned short)bf16r(v1);
                }
            }
        }
    }
    __syncthreads();

    // ---- G3: t2 = h @ W2; y2 = dinv*t2 -> YT[c][j] (K = 64 = 4 chunks) ----
    if (wid < 7) {
        f32x16 a0 = {}, a1 = {};
#pragma unroll
        for (int ch = 0; ch < 4; ++ch) {
            int kb = ch * 32 + hi32 * 16;
            short8 av = *(const short8*)(LDS + LS_BUF2 + grow * 144 + kb);
            short8 bv0 = *(const short8*)(LDS + LS_W2T + gc0 * 144 + kb);
            short8 bv1 = *(const short8*)(LDS + LS_W2T + gc1 * 144 + kb);
            a0 = __builtin_amdgcn_mfma_f32_32x32x16_bf16(av, bv0, a0, 0, 0, 0);
            a1 = __builtin_amdgcn_mfma_f32_32x32x16_bf16(av, bv1, a1, 0, 0, 0);
        }
#pragma unroll
        for (int g = 0; g < 4; ++g) {
            int j0 = tr * 32 + 8 * g + 4 * hi32;
            if (j0 < 200) {
                float4 dv4 = *(const float4*)(LDS + LS_DINV + j0 * 4);
                uint2 u0, u1;
                u0.x = bf16r(dv4.x * a0[4*g+0]) | (bf16r(dv4.y * a0[4*g+1]) << 16);
                u0.y = bf16r(dv4.z * a0[4*g+2]) | (bf16r(dv4.w * a0[4*g+3]) << 16);
                u1.x = bf16r(dv4.x * a1[4*g+0]) | (bf16r(dv4.y * a1[4*g+1]) << 16);
                u1.y = bf16r(dv4.z * a1[4*g+2]) | (bf16r(dv4.w * a1[4*g+3]) << 16);
                *(uint2*)(LDS + LS_YT + gc0 * 464 + j0 * 2) = u0;
                *(uint2*)(LDS + LS_YT + gc1 * 464 + j0 * 2) = u1;
            }
        }
    }
    __syncthreads();

    // ---- G4: z2 = A @ y2; out = relu(dinv_i*(z2 + y2_i) + b2) ----
    if (wid < 7) {
        f32x16 a0 = {}, a1 = {};
#pragma unroll
        for (int ch = 0; ch < 13; ++ch) {
            int kb = ch * 32 + hi32 * 16;
            short8 av = *(const short8*)(LDS + grow * 464 + kb);
            short8 bv0 = *(const short8*)(LDS + LS_YT + gc0 * 464 + kb);
            short8 bv1 = *(const short8*)(LDS + LS_YT + gc1 * 464 + kb);
            a0 = __builtin_amdgcn_mfma_f32_32x32x16_bf16(av, bv0, a0, 0, 0, 0);
            a1 = __builtin_amdgcn_mfma_f32_32x32x16_bf16(av, bv1, a1, 0, 0, 0);
        }
        float bias0 = *(const float*)(LDS + LS_B2 + gc0 * 4);
        float bias1 = *(const float*)(LDS + LS_B2 + gc1 * 4);
#pragma unroll
        for (int g = 0; g < 4; ++g) {
            int i0 = tr * 32 + 8 * g + 4 * hi32;
            if (i0 < 200) {
                float4 dv4 = *(const float4*)(LDS + LS_DINV + i0 * 4);
                uint2 yv0 = *(const uint2*)(LDS + LS_YT + gc0 * 464 + i0 * 2);
                uint2 yv1 = *(const uint2*)(LDS + LS_YT + gc1 * 464 + i0 * 2);
                float* ob = out + ((size_t)b * N + i0) * H;
#pragma unroll
                for (int q = 0; q < 4; ++q) {
                    float dq = (q == 0) ? dv4.x : (q == 1) ? dv4.y : (q == 2) ? dv4.z : dv4.w;
                    unsigned yw0 = (q < 2) ? yv0.x : yv0.y;
                    unsigned yw1 = (q < 2) ? yv1.x : yv1.y;
                    float y0 = bf2f((unsigned short)((q & 1) ? (yw0 >> 16) : (yw0 & 0xffff)));
                    float y1 = bf2f((unsigned short)((q & 1) ? (yw1 >> 16) : (yw1 & 0xffff)));
                    ob[q * H + gc0] = fmaxf(dq * (a0[4*g+q] + y0) + bias0, 0.f);
                    ob[q * H + gc1] = fmaxf(dq * (a1[4*g+q] + y1) + bias1, 0.f);
                }
            }
        }
    }
}

extern "C" void kernel_launch(void* const* d_in, const int* in_sizes, int n_in,
                              void* d_out, int out_size, void* d_ws, size_t ws_size,
                              hipStream_t stream) {
    const float* data = (const float*)d_in[0];
    const float* W1   = (const float*)d_in[1];
    const float* b1   = (const float*)d_in[2];
    const float* W2   = (const float*)d_in[3];
    const float* b2   = (const float*)d_in[4];
    float* out = (float*)d_out;

    hipLaunchKernelGGL(k_fused, dim3(B), dim3(NT), 0, stream, data, W1, b1, W2, b2, out);
}

// Round 13
// 52.134 us; speedup vs baseline: 2.0355x; 1.1029x over previous
//
#include <hip/hip_runtime.h>
#include <math.h>

#define B 512
#define T 256
#define N 200
#define H 64
#define TN (T*N)     // 51200
#define NT 1024      // 16 waves -> 4 waves/SIMD

#define ARS 232              // A image row stride in bf16 (464 B)
#define XTRS 80              // Xt row stride bytes (32 bf16 + 16B pad; 5 slots, odd -> skew)

// ---- fused-kernel LDS map (byte offsets), sequenced by liveness (proven r9-r12) ----
#define LS_S(i)  (25600*(i))            // 4 x [32 t][200 n] f32 staging ring
#define LS_XT(i) (102400 + 16000*(i))   // 2 x [200 n][32 t] bf16 stride 80
#define LS_MUS   92800                  // 800 f32 mu partials (in dead S3 space at tail)
#define LS_VARA  96000                  // 200 f32 raw diag
#define LS_MUA   96800
#define LS_RSA   97600                  // ..98400
#define LS_YT    92800                  // 64 x 464 B  (pads zeroed AFTER stats die)
#define LS_BUF2  122496                 // 64 x 464 B  (W1T, then h; overlaps dead Xt1)
#define LS_W2T   152192                 // 64 x 144 B
#define LS_DINV  161408                 // 200 f32
#define LS_B1    162208
#define LS_B2    162464
#define LS_SZ    162720

typedef short short8 __attribute__((ext_vector_type(8)));
typedef float f32x16 __attribute__((ext_vector_type(16)));

__device__ __forceinline__ unsigned bf16r(float x) {
    unsigned u = __float_as_uint(x);
    return (u + 0x7fffu + ((u >> 16) & 1u)) >> 16;   // round-to-nearest-even
}
__device__ __forceinline__ float bf2f(unsigned short u) {
    return __uint_as_float(((unsigned)u) << 16);
}
__device__ __forceinline__ void gll16(const void* g, void* l) {
    __builtin_amdgcn_global_load_lds(
        (const __attribute__((address_space(1))) unsigned*)g,
        (__attribute__((address_space(3))) unsigned*)l, 16, 0, 0);
}

// counted waitcnt: loads stay in flight ACROSS the raw barrier (T3+T4)
#define WAITV(n) asm volatile("s_waitcnt vmcnt(" #n ") lgkmcnt(0)" ::: "memory")

__global__ __launch_bounds__(NT) void k_fused(const float* __restrict__ data,
                                              const float* __restrict__ W1,
                                              const float* __restrict__ b1f,
                                              const float* __restrict__ W2,
                                              const float* __restrict__ b2f,
                                              float* __restrict__ out) {
    __shared__ __align__(16) unsigned char LDS[LS_SZ];
    const int tid  = threadIdx.x;
    const int b    = blockIdx.x;
    const int lane = tid & 63;
    const int wid  = tid >> 6;          // 0..15
    const int l31  = lane & 31;
    const int hi32 = lane >> 5;
    const float4* db4 = (const float4*)(data + (size_t)b * TN);

    f32x16 acc0 = {}, acc1 = {};
    float mu0 = 0.f;
    float w1r[13], w2r[4];              // tail weight prefetch (c==7)
    const int n0 = tid % 200, q0 = tid / 200;   // transpose unit (tid<800 only)

    // ---- corr tile assignment: 28 upper-tri tiles = 12 A-sharing pairs + 4 singles ----
    int ti, tj0_; bool dual;
    if      (wid == 0)  { ti = 0; tj0_ = 0; dual = true;  }
    else if (wid == 1)  { ti = 0; tj0_ = 2; dual = true;  }
    else if (wid == 2)  { ti = 0; tj0_ = 4; dual = true;  }
    else if (wid == 3)  { ti = 1; tj0_ = 1; dual = true;  }
    else if (wid == 4)  { ti = 1; tj0_ = 3; dual = true;  }
    else if (wid == 5)  { ti = 1; tj0_ = 5; dual = true;  }
    else if (wid == 6)  { ti = 2; tj0_ = 2; dual = true;  }
    else if (wid == 7)  { ti = 2; tj0_ = 4; dual = true;  }
    else if (wid == 8)  { ti = 3; tj0_ = 3; dual = true;  }
    else if (wid == 9)  { ti = 3; tj0_ = 5; dual = true;  }
    else if (wid == 10) { ti = 4; tj0_ = 4; dual = true;  }
    else if (wid == 11) { ti = 5; tj0_ = 5; dual = true;  }
    else if (wid == 12) { ti = 0; tj0_ = 6; dual = false; }
    else if (wid == 13) { ti = 2; tj0_ = 6; dual = false; }
    else if (wid == 14) { ti = 4; tj0_ = 6; dual = false; }
    else                { ti = 6; tj0_ = 6; dual = false; }
    const int tj1_ = tj0_ + 1;
    const bool diag0 = (ti == tj0_);
    int arow = ti * 32 + l31;   if (arow > 199) arow = 199;
    int bc0  = tj0_ * 32 + l31; if (bc0 > 199)  bc0 = 199;
    int bc1  = tj1_ * 32 + l31; if (bc1 > 199)  bc1 = 199;

    auto stage = [&](int cc) {
        const float4* src = db4 + cc * 1600;
        unsigned char* dst = LDS + LS_S(cc & 3);
#pragma unroll
        for (int i = 0; i < 2; ++i) {
            int p = (wid << 1) + i;
            if (p < 25) {
                int idx = (p << 6) + lane;
                gll16(src + idx, dst + idx * 16);
            }
        }
    };
    auto transpose = [&](int c) {
        if (tid < 800) {
            const float* s0 = (const float*)(LDS + LS_S(c & 3)) + (q0 * 8) * 200 + n0;
            unsigned u[4]; float a = 0.f;
#pragma unroll
            for (int j = 0; j < 4; ++j) {
                unsigned b0 = bf16r(s0[(2 * j) * 200]);
                unsigned b1 = bf16r(s0[(2 * j + 1) * 200]);
                a += bf2f((unsigned short)b0) + bf2f((unsigned short)b1);
                u[j] = b0 | (b1 << 16);
            }
            mu0 += a;
            uint4 pk; pk.x = u[0]; pk.y = u[1]; pk.z = u[2]; pk.w = u[3];
            *(uint4*)(LDS + LS_XT(c & 1) + n0 * XTRS + q0 * 16) = pk;
        }
    };
    auto domfma = [&](int cp) {
        const unsigned char* Xp = LDS + LS_XT(cp & 1);
#pragma unroll
        for (int kc = 0; kc < 2; ++kc) {
            int kb = kc * 32 + hi32 * 16;
            short8 a = *(const short8*)(Xp + arow * XTRS + kb);
            short8 b0 = diag0 ? a : *(const short8*)(Xp + bc0 * XTRS + kb);
            acc0 = __builtin_amdgcn_mfma_f32_32x32x16_bf16(a, b0, acc0, 0, 0, 0);
            if (dual) {
                short8 b1 = *(const short8*)(Xp + bc1 * XTRS + kb);
                acc1 = __builtin_amdgcn_mfma_f32_32x32x16_bf16(a, b1, acc1, 0, 0, 0);
            }
        }
    };

    // ---- corr K-loop: 3-deep prefetch, counted vmcnt, raw barriers ----
    // stage(c+3) writes slot (c+3)&3 == (c-1)&3, whose reader transpose(c-1)
    // completed before barrier(c) in every wave -> issuing AFTER the barrier is
    // race-free (stage-before-barrier at depth 3 would race, round-8 lesson).
    stage(0); stage(1); stage(2);
#pragma unroll
    for (int c = 0; c < 8; ++c) {
        if (wid < 12)       { if (c < 6) WAITV(4); else if (c == 6) WAITV(2); else WAITV(0); }
        else if (wid == 12) { if (c < 6) WAITV(2); else if (c == 6) WAITV(1); else WAITV(0); }
        else                { WAITV(0); }
        __builtin_amdgcn_sched_barrier(0);
        __builtin_amdgcn_s_barrier();        // S[c] + Xt[c-1] now valid for all waves
        __builtin_amdgcn_sched_barrier(0);
        if (c < 5) stage(c + 3);
        if (c == 7) {                        // weight prefetch: issued after last WAITV,
#pragma unroll                               // drained by compiler vmcnt at weight phase
            for (int i = 0; i < 12; ++i) w1r[i] = W1[tid + i * 1024];
            if (tid < 512) w1r[12] = W1[tid + 12288];
#pragma unroll
            for (int i = 0; i < 4; ++i) w2r[i] = W2[tid + i * 1024];
        }
        if (c > 0) domfma(c - 1);
        transpose(c);
    }
    asm volatile("s_waitcnt lgkmcnt(0)" ::: "memory");
    __builtin_amdgcn_s_barrier();            // publish Xt[7]
    __builtin_amdgcn_sched_barrier(0);
    domfma(7);
    asm volatile("s_waitcnt lgkmcnt(0)" ::: "memory");
    __builtin_amdgcn_s_barrier();            // Xt dead -> BUF2 (overlaps Xt1) writable
    __builtin_amdgcn_sched_barrier(0);

    // ---- weight staging (from prefetched regs) + mu partials + raw diag ----
#pragma unroll
    for (int i = 0; i < 13; ++i) {
        int e = tid + i * 1024;
        if (i < 12 || tid < 512) {
            int k = e >> 6, l = e & 63;
            *(unsigned short*)(LDS + LS_BUF2 + l * 464 + k * 2) = (unsigned short)bf16r(w1r[i]);
        }
    }
    for (int e = tid; e < 64 * 16; e += NT) {             // W1T pads = 0
        int l = e >> 4, d = e & 15;
        *(unsigned*)(LDS + LS_BUF2 + l * 464 + 400 + d * 4) = 0;
    }
#pragma unroll
    for (int i = 0; i < 4; ++i) {
        int e = tid + i * 1024;
        int k = e >> 6, l = e & 63;
        *(unsigned short*)(LDS + LS_W2T + l * 144 + k * 2) = (unsigned short)bf16r(w2r[i]);
    }
    if (tid < 64) *(float*)(LDS + LS_B1 + tid * 4) = b1f[tid];
    else if (tid < 128) *(float*)(LDS + LS_B2 + (tid - 64) * 4) = b2f[tid - 64];

    if (tid < 800) *(float*)(LDS + LS_MUS + tid * 4) = mu0;   // slot q0*200+n0 == tid
    if (diag0) {
#pragma unroll
        for (int r = 0; r < 16; ++r) {
            int rowin = (r & 3) + 8 * (r >> 2) + 4 * hi32;
            int n = ti * 32 + rowin;
            if (l31 == rowin && n < 200)
                *(float*)(LDS + LS_VARA + n * 4) = acc0[r];   // S_nn
        }
    }
    __syncthreads();

    // ---- per-node mu, rs ----
    if (tid < 200) {
        float s = *(const float*)(LDS + LS_MUS + tid * 4)
                + *(const float*)(LDS + LS_MUS + 800 + tid * 4)
                + *(const float*)(LDS + LS_MUS + 1600 + tid * 4)
                + *(const float*)(LDS + LS_MUS + 2400 + tid * 4);
        float mu = s * (1.f / 256.f);
        float var = *(const float*)(LDS + LS_VARA + tid * 4) - 256.f * mu * mu;
        *(float*)(LDS + LS_MUA + tid * 4) = mu;
        *(float*)(LDS + LS_RSA + tid * 4) = (var > 0.f) ? rsqrtf(var) : 0.f;
    }
    __syncthreads();

    // ---- epilogue: |corr| -> image [200][232] bf16 (packed transposed quads +
    // scalar off-diag region; MFMA tile bit-exact symmetric, r11 derivation) ----
    unsigned short* A16 = (unsigned short*)LDS;
    auto epi = [&](const f32x16& ac, int ib, int jb) {
        int col = jb + l31;
        if (col < 200) {
            float muc = *(const float*)(LDS + LS_MUA + col * 4);
            float rsc = *(const float*)(LDS + LS_RSA + col * 4);
            unsigned short cv[16];
#pragma unroll
            for (int g = 0; g < 4; ++g) {
                int rb = ib + 8 * g + 4 * hi32;           // quad base row (mult of 4)
                float4 mur4 = *(const float4*)(LDS + LS_MUA + rb * 4);  // may read junk
                float4 rsr4 = *(const float4*)(LDS + LS_RSA + rb * 4);  // (writes guarded)
                cv[4*g+0] = (unsigned short)bf16r(fabsf((ac[4*g+0] - 256.f * mur4.x * muc) * (rsr4.x * rsc)));
                cv[4*g+1] = (unsigned short)bf16r(fabsf((ac[4*g+1] - 256.f * mur4.y * muc) * (rsr4.y * rsc)));
                cv[4*g+2] = (unsigned short)bf16r(fabsf((ac[4*g+2] - 256.f * mur4.z * muc) * (rsr4.z * rsc)));
                cv[4*g+3] = (unsigned short)bf16r(fabsf((ac[4*g+3] - 256.f * mur4.w * muc) * (rsr4.w * rsc)));
                if (rb < 200) {
                    uint2 uu;
                    uu.x = (unsigned)cv[4*g+0] | ((unsigned)cv[4*g+1] << 16);
                    uu.y = (unsigned)cv[4*g+2] | ((unsigned)cv[4*g+3] << 16);
                    *(uint2*)(LDS + col * 464 + rb * 2) = uu;   // image[col][rb..rb+3]
                }
            }
            if (ib != jb) {
#pragma unroll
                for (int r = 0; r < 16; ++r) {
                    int row = ib + (r & 3) + 8 * (r >> 2) + 4 * hi32;
                    if (row < 200) A16[row * ARS + col] = cv[r];
                }
            }
        }
    };
    epi(acc0, ti * 32, tj0_ * 32);
    if (dual) epi(acc1, ti * 32, tj1_ * 32);
    for (int e = tid; e < 3200; e += NT) {                // image pad cols 200..231 = 0
        int row = e >> 4, pc = e & 15;
        *(unsigned*)(LDS + row * 464 + 400 + pc * 4) = 0;
    }
    __syncthreads();                                      // stats dead from here on

    // ---- row sums -> dinv: 4 threads/row + shfl combine (latency/4) ----
    if (tid < 800) {
        int row = tid >> 2, part = tid & 3;
        int sl0 = part * 7, ns = (part == 3) ? 8 : 7;
        float s = (part == 0) ? 1.f : 0.f;                // the +I
#pragma unroll
        for (int e2 = 0; e2 < 8; ++e2) {
            if (e2 < ns) {
                short8 v = *(const short8*)(LDS + row * 464 + (sl0 + e2) * 16);
#pragma unroll
                for (int j = 0; j < 8; ++j) s += bf2f((unsigned short)v[j]);
            }
        }
        s += __shfl_xor(s, 1);
        s += __shfl_xor(s, 2);
        if (part == 0) *(float*)(LDS + LS_DINV + row * 4) = rsqrtf(s);
    }
    for (int e = tid; e < 64 * 16; e += NT) {             // YT pads = 0 (stats now dead)
        int l = e >> 4, d = e & 15;
        *(unsigned*)(LDS + LS_YT + l * 464 + 400 + d * 4) = 0;
    }
    __syncthreads();

    // ============ GCN: 32x32x16 MFMA, 7 waves x (1 row-tile x BOTH col-tiles) ========
    const int tr = wid;                                   // row-tile (wid<7)
    const int gc0 = l31, gc1 = 32 + l31;                  // the two output channels
    int grow = tr * 32 + l31; if (grow > 199) grow = 199; // A-frag row (clamped dup)

    // ---- G1: t1 = A @ W1; y = dinv*t1 -> YT[c][j] ----
    if (wid < 7) {
        f32x16 a0 = {}, a1 = {};
#pragma unroll
        for (int ch = 0; ch < 13; ++ch) {
            int kb = ch * 32 + hi32 * 16;
            short8 av = *(const short8*)(LDS + grow * 464 + kb);
            short8 bv0 = *(const short8*)(LDS + LS_BUF2 + gc0 * 464 + kb);
            short8 bv1 = *(const short8*)(LDS + LS_BUF2 + gc1 * 464 + kb);
            a0 = __builtin_amdgcn_mfma_f32_32x32x16_bf16(av, bv0, a0, 0, 0, 0);
            a1 = __builtin_amdgcn_mfma_f32_32x32x16_bf16(av, bv1, a1, 0, 0, 0);
        }
#pragma unroll
        for (int g = 0; g < 4; ++g) {
            int j0 = tr * 32 + 8 * g + 4 * hi32;
            if (j0 < 200) {
                float4 dv4 = *(const float4*)(LDS + LS_DINV + j0 * 4);
                uint2 u0, u1;
                u0.x = bf16r(dv4.x * a0[4*g+0]) | (bf16r(dv4.y * a0[4*g+1]) << 16);
                u0.y = bf16r(dv4.z * a0[4*g+2]) | (bf16r(dv4.w * a0[4*g+3]) << 16);
                u1.x = bf16r(dv4.x * a1[4*g+0]) | (bf16r(dv4.y * a1[4*g+1]) << 16);
                u1.y = bf16r(dv4.z * a1[4*g+2]) | (bf16r(dv4.w * a1[4*g+3]) << 16);
                *(uint2*)(LDS + LS_YT + gc0 * 464 + j0 * 2) = u0;
                *(uint2*)(LDS + LS_YT + gc1 * 464 + j0 * 2) = u1;
            }
        }
    }
    __syncthreads();

    // ---- G2: z = A @ y; h = relu(dinv_i*(z + y_i) + b1) -> BUF2[i][c] ----
    if (wid < 7) {
        f32x16 a0 = {}, a1 = {};
#pragma unroll
        for (int ch = 0; ch < 13; ++ch) {
            int kb = ch * 32 + hi32 * 16;
            short8 av = *(const short8*)(LDS + grow * 464 + kb);
            short8 bv0 = *(const short8*)(LDS + LS_YT + gc0 * 464 + kb);
            short8 bv1 = *(const short8*)(LDS + LS_YT + gc1 * 464 + kb);
            a0 = __builtin_amdgcn_mfma_f32_32x32x16_bf16(av, bv0, a0, 0, 0, 0);
            a1 = __builtin_amdgcn_mfma_f32_32x32x16_bf16(av, bv1, a1, 0, 0, 0);
        }
        float bias0 = *(const float*)(LDS + LS_B1 + gc0 * 4);
        float bias1 = *(const float*)(LDS + LS_B1 + gc1 * 4);
#pragma unroll
        for (int g = 0; g < 4; ++g) {
            int i0 = tr * 32 + 8 * g + 4 * hi32;
            if (i0 < 200) {
                float4 dv4 = *(const float4*)(LDS + LS_DINV + i0 * 4);
                uint2 yv0 = *(const uint2*)(LDS + LS_YT + gc0 * 464 + i0 * 2);
                uint2 yv1 = *(const uint2*)(LDS + LS_YT + gc1 * 464 + i0 * 2);
#pragma unroll
                for (int q = 0; q < 4; ++q) {
                    float dq = (q == 0) ? dv4.x : (q == 1) ? dv4.y : (q == 2) ? dv4.z : dv4.w;
                    unsigned yw0 = (q < 2) ? yv0.x : yv0.y;
                    unsigned yw1 = (q < 2) ? yv1.x : yv1.y;
                    float y0 = bf2f((unsigned short)((q & 1) ? (yw0 >> 16) : (yw0 & 0xffff)));
                    float y1 = bf2f((unsigned short)((q & 1) ? (yw1 >> 16) : (yw1 & 0xffff)));
                    float v0 = fmaxf(dq * (a0[4*g+q] + y0) + bias0, 0.f);
                    float v1 = fmaxf(dq * (a1[4*g+q] + y1) + bias1, 0.f);
                    *(unsigned short*)(LDS + LS_BUF2 + (i0 + q) * 144 + gc0 * 2) = (unsigned short)bf16r(v0);
                    *(unsigned short*)(LDS + LS_BUF2 + (i0 + q) * 144 + gc1 * 2) = (unsigned short)bf16r(v1);
                }
            }
        }
    }
    __syncthreads();

    // ---- G3: t2 = h @ W2; y2 = dinv*t2 -> YT[c][j] (K = 64 = 4 chunks) ----
    if (wid < 7) {
        f32x16 a0 = {}, a1 = {};
#pragma unroll
        for (int ch = 0; ch < 4; ++ch) {
            int kb = ch * 32 + hi32 * 16;
            short8 av = *(const short8*)(LDS + LS_BUF2 + grow * 144 + kb);
            short8 bv0 = *(const short8*)(LDS + LS_W2T + gc0 * 144 + kb);
            short8 bv1 = *(const short8*)(LDS + LS_W2T + gc1 * 144 + kb);
            a0 = __builtin_amdgcn_mfma_f32_32x32x16_bf16(av, bv0, a0, 0, 0, 0);
            a1 = __builtin_amdgcn_mfma_f32_32x32x16_bf16(av, bv1, a1, 0, 0, 0);
        }
#pragma unroll
        for (int g = 0; g < 4; ++g) {
            int j0 = tr * 32 + 8 * g + 4 * hi32;
            if (j0 < 200) {
                float4 dv4 = *(const float4*)(LDS + LS_DINV + j0 * 4);
                uint2 u0, u1;
                u0.x = bf16r(dv4.x * a0[4*g+0]) | (bf16r(dv4.y * a0[4*g+1]) << 16);
                u0.y = bf16r(dv4.z * a0[4*g+2]) | (bf16r(dv4.w * a0[4*g+3]) << 16);
                u1.x = bf16r(dv4.x * a1[4*g+0]) | (bf16r(dv4.y * a1[4*g+1]) << 16);
                u1.y = bf16r(dv4.z * a1[4*g+2]) | (bf16r(dv4.w * a1[4*g+3]) << 16);
                *(uint2*)(LDS + LS_YT + gc0 * 464 + j0 * 2) = u0;
                *(uint2*)(LDS + LS_YT + gc1 * 464 + j0 * 2) = u1;
            }
        }
    }
    __syncthreads();

    // ---- G4: z2 = A @ y2; out = relu(dinv_i*(z2 + y2_i) + b2) ----
    if (wid < 7) {
        f32x16 a0 = {}, a1 = {};
#pragma unroll
        for (int ch = 0; ch < 13; ++ch) {
            int kb = ch * 32 + hi32 * 16;
            short8 av = *(const short8*)(LDS + grow * 464 + kb);
            short8 bv0 = *(const short8*)(LDS + LS_YT + gc0 * 464 + kb);
            short8 bv1 = *(const short8*)(LDS + LS_YT + gc1 * 464 + kb);
            a0 = __builtin_amdgcn_mfma_f32_32x32x16_bf16(av, bv0, a0, 0, 0, 0);
            a1 = __builtin_amdgcn_mfma_f32_32x32x16_bf16(av, bv1, a1, 0, 0, 0);
        }
        float bias0 = *(const float*)(LDS + LS_B2 + gc0 * 4);
        float bias1 = *(const float*)(LDS + LS_B2 + gc1 * 4);
#pragma unroll
        for (int g = 0; g < 4; ++g) {
            int i0 = tr * 32 + 8 * g + 4 * hi32;
            if (i0 < 200) {
                float4 dv4 = *(const float4*)(LDS + LS_DINV + i0 * 4);
                uint2 yv0 = *(const uint2*)(LDS + LS_YT + gc0 * 464 + i0 * 2);
                uint2 yv1 = *(const uint2*)(LDS + LS_YT + gc1 * 464 + i0 * 2);
                float* ob = out + ((size_t)b * N + i0) * H;
#pragma unroll
                for (int q = 0; q < 4; ++q) {
                    float dq = (q == 0) ? dv4.x : (q == 1) ? dv4.y : (q == 2) ? dv4.z : dv4.w;
                    unsigned yw0 = (q < 2) ? yv0.x : yv0.y;
                    unsigned yw1 = (q < 2) ? yv1.x : yv1.y;
                    float y0 = bf2f((unsigned short)((q & 1) ? (yw0 >> 16) : (yw0 & 0xffff)));
                    float y1 = bf2f((unsigned short)((q & 1) ? (yw1 >> 16) : (yw1 & 0xffff)));
                    ob[q * H + gc0] = fmaxf(dq * (a0[4*g+q] + y0) + bias0, 0.f);
                    ob[q * H + gc1] = fmaxf(dq * (a1[4*g+q] + y1) + bias1, 0.f);
                }
            }
        }
    }
}

extern "C" void kernel_launch(void* const* d_in, const int* in_sizes, int n_in,
                              void* d_out, int out_size, void* d_ws, size_t ws_size,
                              hipStream_t stream) {
    const float* data = (const float*)d_in[0];
    const float* W1   = (const float*)d_in[1];
    const float* b1   = (const float*)d_in[2];
    const float* W2   = (const float*)d_in[3];
    const float* b2   = (const float*)d_in[4];
    float* out = (float*)d_out;

    hipLaunchKernelGGL(k_fused, dim3(B), dim3(NT), 0, stream, data, W1, b1, W2, b2, out);
}

// Round 14
// 50.157 us; speedup vs baseline: 2.1158x; 1.0394x over previous
//
#include <hip/hip_runtime.h>
#include <math.h>

#define B 512
#define T 256
#define N 200
#define H 64
#define TN (T*N)     // 51200
#define NT 1024      // 16 waves -> 4 waves/SIMD

#define ARS 232              // A image row stride in bf16 (464 B)
#define XTRS 80              // Xt row stride bytes (32 bf16 + 16B pad; 5 slots, odd -> skew)

// ---- fused-kernel LDS map (byte offsets), sequenced by liveness ----
// corr phase: Xt0/Xt1 [102400,134400) + stats [92800,98400); region [0,92800)
//             untouched until the epilogue writes the A image there.
// gcn  phase: image [0,92800) | YT | BUF2(W1T->h) | W2T | DINV | B1 | B2
#define LS_XT(i) (102400 + 16000*(i))   // 2 x [200 n][32 t] bf16 stride 80
#define LS_MUS   92800                  // 800 f32 mu partials
#define LS_VARA  96000                  // 200 f32 raw diag
#define LS_MUA   96800
#define LS_RSA   97600                  // ..98400
#define LS_YT    92800                  // 64 x 464 B  (pads zeroed AFTER stats die)
#define LS_BUF2  122496                 // 64 x 464 B  (W1T, then h; overlaps dead Xt1)
#define LS_W2T   152192                 // 64 x 144 B
#define LS_DINV  161408                 // 200 f32
#define LS_B1    162208
#define LS_B2    162464
#define LS_SZ    162720

typedef short short8 __attribute__((ext_vector_type(8)));
typedef float f32x16 __attribute__((ext_vector_type(16)));

__device__ __forceinline__ unsigned bf16r(float x) {
    unsigned u = __float_as_uint(x);
    return (u + 0x7fffu + ((u >> 16) & 1u)) >> 16;   // round-to-nearest-even
}
__device__ __forceinline__ float bf2f(unsigned short u) {
    return __uint_as_float(((unsigned)u) << 16);
}

__global__ __launch_bounds__(NT) void k_fused(const float* __restrict__ data,
                                              const float* __restrict__ W1,
                                              const float* __restrict__ b1f,
                                              const float* __restrict__ W2,
                                              const float* __restrict__ b2f,
                                              float* __restrict__ out) {
    __shared__ __align__(16) unsigned char LDS[LS_SZ];
    const int tid  = threadIdx.x;
    const int b    = blockIdx.x;
    const int lane = tid & 63;
    const int wid  = tid >> 6;          // 0..15
    const int l31  = lane & 31;
    const int hi32 = lane >> 5;
    const float* dbase = data + (size_t)b * TN;

    f32x16 acc0 = {}, acc1 = {};
    float mu0 = 0.f;
    float w1r[13], w2r[4];              // tail weight prefetch (c==7)
    float rA[8], rB[8];                 // direct-register chunk buffers (no LDS staging)
    const int n0 = tid % 200, q0 = tid / 200;   // transpose unit (tid<800 only)

    // ---- corr tile assignment: 28 upper-tri tiles = 12 A-sharing pairs + 4 singles ----
    int ti, tj0_; bool dual;
    if      (wid == 0)  { ti = 0; tj0_ = 0; dual = true;  }
    else if (wid == 1)  { ti = 0; tj0_ = 2; dual = true;  }
    else if (wid == 2)  { ti = 0; tj0_ = 4; dual = true;  }
    else if (wid == 3)  { ti = 1; tj0_ = 1; dual = true;  }
    else if (wid == 4)  { ti = 1; tj0_ = 3; dual = true;  }
    else if (wid == 5)  { ti = 1; tj0_ = 5; dual = true;  }
    else if (wid == 6)  { ti = 2; tj0_ = 2; dual = true;  }
    else if (wid == 7)  { ti = 2; tj0_ = 4; dual = true;  }
    else if (wid == 8)  { ti = 3; tj0_ = 3; dual = true;  }
    else if (wid == 9)  { ti = 3; tj0_ = 5; dual = true;  }
    else if (wid == 10) { ti = 4; tj0_ = 4; dual = true;  }
    else if (wid == 11) { ti = 5; tj0_ = 5; dual = true;  }
    else if (wid == 12) { ti = 0; tj0_ = 6; dual = false; }
    else if (wid == 13) { ti = 2; tj0_ = 6; dual = false; }
    else if (wid == 14) { ti = 4; tj0_ = 6; dual = false; }
    else                { ti = 6; tj0_ = 6; dual = false; }
    const int tj1_ = tj0_ + 1;
    const bool diag0 = (ti == tj0_);
    int arow = ti * 32 + l31;   if (arow > 199) arow = 199;
    int bc0  = tj0_ * 32 + l31; if (bc0 > 199)  bc0 = 199;
    int bc1  = tj1_ * 32 + l31; if (bc1 > 199)  bc1 = 199;

    // load chunk cc straight into registers: 8 coalesced b32 loads per thread
    auto ldchunk = [&](int cc, float* r) {
        if (tid < 800) {
            const float* src = dbase + (cc * 32 + q0 * 8) * 200 + n0;
#pragma unroll
            for (int j = 0; j < 8; ++j) r[j] = src[j * 200];
        }
    };
    // pack chunk c from registers -> Xt[c&1] bf16 [200n][32t] (+ mu partial, same order)
    auto pack = [&](int c, const float* r) {
        if (tid < 800) {
            unsigned u[4]; float a = 0.f;
#pragma unroll
            for (int j = 0; j < 4; ++j) {
                unsigned b0 = bf16r(r[2 * j]);
                unsigned b1 = bf16r(r[2 * j + 1]);
                a += bf2f((unsigned short)b0) + bf2f((unsigned short)b1);
                u[j] = b0 | (b1 << 16);
            }
            mu0 += a;
            uint4 pk; pk.x = u[0]; pk.y = u[1]; pk.z = u[2]; pk.w = u[3];
            *(uint4*)(LDS + LS_XT(c & 1) + n0 * XTRS + q0 * 16) = pk;
        }
    };
    auto domfma = [&](int cp) {
        const unsigned char* Xp = LDS + LS_XT(cp & 1);
#pragma unroll
        for (int kc = 0; kc < 2; ++kc) {
            int kb = kc * 32 + hi32 * 16;
            short8 a = *(const short8*)(Xp + arow * XTRS + kb);
            short8 b0 = diag0 ? a : *(const short8*)(Xp + bc0 * XTRS + kb);
            acc0 = __builtin_amdgcn_mfma_f32_32x32x16_bf16(a, b0, acc0, 0, 0, 0);
            if (dual) {
                short8 b1 = *(const short8*)(Xp + bc1 * XTRS + kb);
                acc1 = __builtin_amdgcn_mfma_f32_32x32x16_bf16(a, b1, acc1, 0, 0, 0);
            }
        }
    };

    // ---- corr K-loop: register loads 2 regions ahead; ONE barrier per chunk.
    // Region between barriers = { mfma(c-1) ; pack(c) ; issue loads(c+2) }.
    // pack(c+1) writes Xt[(c+1)&1] == Xt[(c-1)&1], separated from mfma(c-1)'s
    // reads by barrier(c) (lgkmcnt(0) drains both reads and writes per wave).
    ldchunk(0, rA); ldchunk(1, rB);
#pragma unroll
    for (int c = 0; c < 8; ++c) {
        if (c & 1) pack(c, rB); else pack(c, rA);
        if (c < 6) { if (c & 1) ldchunk(c + 2, rB); else ldchunk(c + 2, rA); }
        if (c == 7) {                        // weight prefetch: overlaps mfma(7)+tail
#pragma unroll
            for (int i = 0; i < 12; ++i) w1r[i] = W1[tid + i * 1024];
            if (tid < 512) w1r[12] = W1[tid + 12288];
#pragma unroll
            for (int i = 0; i < 4; ++i) w2r[i] = W2[tid + i * 1024];
        }
        asm volatile("s_waitcnt lgkmcnt(0)" ::: "memory");
        __builtin_amdgcn_sched_barrier(0);
        __builtin_amdgcn_s_barrier();        // publish Xt[c&1]
        __builtin_amdgcn_sched_barrier(0);
        domfma(c);
    }
    asm volatile("s_waitcnt lgkmcnt(0)" ::: "memory");
    __builtin_amdgcn_sched_barrier(0);
    __builtin_amdgcn_s_barrier();            // Xt dead -> BUF2 (overlaps Xt1) writable
    __builtin_amdgcn_sched_barrier(0);

    // ---- weight staging (from prefetched regs) + mu partials + raw diag ----
#pragma unroll
    for (int i = 0; i < 13; ++i) {
        int e = tid + i * 1024;
        if (i < 12 || tid < 512) {
            int k = e >> 6, l = e & 63;
            *(unsigned short*)(LDS + LS_BUF2 + l * 464 + k * 2) = (unsigned short)bf16r(w1r[i]);
        }
    }
    for (int e = tid; e < 64 * 16; e += NT) {             // W1T pads = 0
        int l = e >> 4, d = e & 15;
        *(unsigned*)(LDS + LS_BUF2 + l * 464 + 400 + d * 4) = 0;
    }
#pragma unroll
    for (int i = 0; i < 4; ++i) {
        int e = tid + i * 1024;
        int k = e >> 6, l = e & 63;
        *(unsigned short*)(LDS + LS_W2T + l * 144 + k * 2) = (unsigned short)bf16r(w2r[i]);
    }
    if (tid < 64) *(float*)(LDS + LS_B1 + tid * 4) = b1f[tid];
    else if (tid < 128) *(float*)(LDS + LS_B2 + (tid - 64) * 4) = b2f[tid - 64];

    if (tid < 800) *(float*)(LDS + LS_MUS + tid * 4) = mu0;   // slot q0*200+n0 == tid
    if (diag0) {
#pragma unroll
        for (int r = 0; r < 16; ++r) {
            int rowin = (r & 3) + 8 * (r >> 2) + 4 * hi32;
            int n = ti * 32 + rowin;
            if (l31 == rowin && n < 200)
                *(float*)(LDS + LS_VARA + n * 4) = acc0[r];   // S_nn
        }
    }
    __syncthreads();

    // ---- per-node mu, rs ----
    if (tid < 200) {
        float s = *(const float*)(LDS + LS_MUS + tid * 4)
                + *(const float*)(LDS + LS_MUS + 800 + tid * 4)
                + *(const float*)(LDS + LS_MUS + 1600 + tid * 4)
                + *(const float*)(LDS + LS_MUS + 2400 + tid * 4);
        float mu = s * (1.f / 256.f);
        float var = *(const float*)(LDS + LS_VARA + tid * 4) - 256.f * mu * mu;
        *(float*)(LDS + LS_MUA + tid * 4) = mu;
        *(float*)(LDS + LS_RSA + tid * 4) = (var > 0.f) ? rsqrtf(var) : 0.f;
    }
    __syncthreads();

    // ---- epilogue: |corr| -> image [200][232] bf16 (packed transposed quads +
    // scalar off-diag region; MFMA tile bit-exact symmetric, r11 derivation) ----
    unsigned short* A16 = (unsigned short*)LDS;
    auto epi = [&](const f32x16& ac, int ib, int jb) {
        int col = jb + l31;
        if (col < 200) {
            float muc = *(const float*)(LDS + LS_MUA + col * 4);
            float rsc = *(const float*)(LDS + LS_RSA + col * 4);
            unsigned short cv[16];
#pragma unroll
            for (int g = 0; g < 4; ++g) {
                int rb = ib + 8 * g + 4 * hi32;           // quad base row (mult of 4)
                float4 mur4 = *(const float4*)(LDS + LS_MUA + rb * 4);  // may read junk
                float4 rsr4 = *(const float4*)(LDS + LS_RSA + rb * 4);  // (writes guarded)
                cv[4*g+0] = (unsigned short)bf16r(fabsf((ac[4*g+0] - 256.f * mur4.x * muc) * (rsr4.x * rsc)));
                cv[4*g+1] = (unsigned short)bf16r(fabsf((ac[4*g+1] - 256.f * mur4.y * muc) * (rsr4.y * rsc)));
                cv[4*g+2] = (unsigned short)bf16r(fabsf((ac[4*g+2] - 256.f * mur4.z * muc) * (rsr4.z * rsc)));
                cv[4*g+3] = (unsigned short)bf16r(fabsf((ac[4*g+3] - 256.f * mur4.w * muc) * (rsr4.w * rsc)));
                if (rb < 200) {
                    uint2 uu;
                    uu.x = (unsigned)cv[4*g+0] | ((unsigned)cv[4*g+1] << 16);
                    uu.y = (unsigned)cv[4*g+2] | ((unsigned)cv[4*g+3] << 16);
                    *(uint2*)(LDS + col * 464 + rb * 2) = uu;   // image[col][rb..rb+3]
                }
            }
            if (ib != jb) {
#pragma unroll
                for (int r = 0; r < 16; ++r) {
                    int row = ib + (r & 3) + 8 * (r >> 2) + 4 * hi32;
                    if (row < 200) A16[row * ARS + col] = cv[r];
                }
            }
        }
    };
    epi(acc0, ti * 32, tj0_ * 32);
    if (dual) epi(acc1, ti * 32, tj1_ * 32);
    for (int e = tid; e < 3200; e += NT) {                // image pad cols 200..231 = 0
        int row = e >> 4, pc = e & 15;
        *(unsigned*)(LDS + row * 464 + 400 + pc * 4) = 0;
    }
    __syncthreads();                                      // stats dead from here on

    // ---- row sums -> dinv: 4 threads/row + shfl combine ----
    if (tid < 800) {
        int row = tid >> 2, part = tid & 3;
        int sl0 = part * 7, ns = (part == 3) ? 8 : 7;
        float s = (part == 0) ? 1.f : 0.f;                // the +I
#pragma unroll
        for (int e2 = 0; e2 < 8; ++e2) {
            if (e2 < ns) {
                short8 v = *(const short8*)(LDS + row * 464 + (sl0 + e2) * 16);
#pragma unroll
                for (int j = 0; j < 8; ++j) s += bf2f((unsigned short)v[j]);
            }
        }
        s += __shfl_xor(s, 1);
        s += __shfl_xor(s, 2);
        if (part == 0) *(float*)(LDS + LS_DINV + row * 4) = rsqrtf(s);
    }
    for (int e = tid; e < 64 * 16; e += NT) {             // YT pads = 0 (stats now dead)
        int l = e >> 4, d = e & 15;
        *(unsigned*)(LDS + LS_YT + l * 464 + 400 + d * 4) = 0;
    }
    __syncthreads();

    // ============ GCN: 32x32x16 MFMA, 7 waves x (1 row-tile x BOTH col-tiles) ========
    const int tr = wid;                                   // row-tile (wid<7)
    const int gc0 = l31, gc1 = 32 + l31;                  // the two output channels
    int grow = tr * 32 + l31; if (grow > 199) grow = 199; // A-frag row (clamped dup)

    // ---- G1: t1 = A @ W1; y = dinv*t1 -> YT[c][j] ----
    if (wid < 7) {
        f32x16 a0 = {}, a1 = {};
#pragma unroll
        for (int ch = 0; ch < 13; ++ch) {
            int kb = ch * 32 + hi32 * 16;
            short8 av = *(const short8*)(LDS + grow * 464 + kb);
            short8 bv0 = *(const short8*)(LDS + LS_BUF2 + gc0 * 464 + kb);
            short8 bv1 = *(const short8*)(LDS + LS_BUF2 + gc1 * 464 + kb);
            a0 = __builtin_amdgcn_mfma_f32_32x32x16_bf16(av, bv0, a0, 0, 0, 0);
            a1 = __builtin_amdgcn_mfma_f32_32x32x16_bf16(av, bv1, a1, 0, 0, 0);
        }
#pragma unroll
        for (int g = 0; g < 4; ++g) {
            int j0 = tr * 32 + 8 * g + 4 * hi32;
            if (j0 < 200) {
                float4 dv4 = *(const float4*)(LDS + LS_DINV + j0 * 4);
                uint2 u0, u1;
                u0.x = bf16r(dv4.x * a0[4*g+0]) | (bf16r(dv4.y * a0[4*g+1]) << 16);
                u0.y = bf16r(dv4.z * a0[4*g+2]) | (bf16r(dv4.w * a0[4*g+3]) << 16);
                u1.x = bf16r(dv4.x * a1[4*g+0]) | (bf16r(dv4.y * a1[4*g+1]) << 16);
                u1.y = bf16r(dv4.z * a1[4*g+2]) | (bf16r(dv4.w * a1[4*g+3]) << 16);
                *(uint2*)(LDS + LS_YT + gc0 * 464 + j0 * 2) = u0;
                *(uint2*)(LDS + LS_YT + gc1 * 464 + j0 * 2) = u1;
            }
        }
    }
    __syncthreads();

    // ---- G2: z = A @ y; h = relu(dinv_i*(z + y_i) + b1) -> BUF2[i][c] ----
    if (wid < 7) {
        f32x16 a0 = {}, a1 = {};
#pragma unroll
        for (int ch = 0; ch < 13; ++ch) {
            int kb = ch * 32 + hi32 * 16;
            short8 av = *(const short8*)(LDS + grow * 464 + kb);
            short8 bv0 = *(const short8*)(LDS + LS_YT + gc0 * 464 + kb);
            short8 bv1 = *(const short8*)(LDS + LS_YT + gc1 * 464 + kb);
            a0 = __builtin_amdgcn_mfma_f32_32x32x16_bf16(av, bv0, a0, 0, 0, 0);
            a1 = __builtin_amdgcn_mfma_f32_32x32x16_bf16(av, bv1, a1, 0, 0, 0);
        }
        float bias0 = *(const float*)(LDS + LS_B1 + gc0 * 4);
        float bias1 = *(const float*)(LDS + LS_B1 + gc1 * 4);
#pragma unroll
        for (int g = 0; g < 4; ++g) {
            int i0 = tr * 32 + 8 * g + 4 * hi32;
            if (i0 < 200) {
                float4 dv4 = *(const float4*)(LDS + LS_DINV + i0 * 4);
                uint2 yv0 = *(const uint2*)(LDS + LS_YT + gc0 * 464 + i0 * 2);
                uint2 yv1 = *(const uint2*)(LDS + LS_YT + gc1 * 464 + i0 * 2);
#pragma unroll
                for (int q = 0; q < 4; ++q) {
                    float dq = (q == 0) ? dv4.x : (q == 1) ? dv4.y : (q == 2) ? dv4.z : dv4.w;
                    unsigned yw0 = (q < 2) ? yv0.x : yv0.y;
                    unsigned yw1 = (q < 2) ? yv1.x : yv1.y;
                    float y0 = bf2f((unsigned short)((q & 1) ? (yw0 >> 16) : (yw0 & 0xffff)));
                    float y1 = bf2f((unsigned short)((q & 1) ? (yw1 >> 16) : (yw1 & 0xffff)));
                    float v0 = fmaxf(dq * (a0[4*g+q] + y0) + bias0, 0.f);
                    float v1 = fmaxf(dq * (a1[4*g+q] + y1) + bias1, 0.f);
                    *(unsigned short*)(LDS + LS_BUF2 + (i0 + q) * 144 + gc0 * 2) = (unsigned short)bf16r(v0);
                    *(unsigned short*)(LDS + LS_BUF2 + (i0 + q) * 144 + gc1 * 2) = (unsigned short)bf16r(v1);
                }
            }
        }
    }
    __syncthreads();

    // ---- G3: t2 = h @ W2; y2 = dinv*t2 -> YT[c][j] (K = 64 = 4 chunks) ----
    if (wid < 7) {
        f32x16 a0 = {}, a1 = {};
#pragma unroll
        for (int ch = 0; ch < 4; ++ch) {
            int kb = ch * 32 + hi32 * 16;
            short8 av = *(const short8*)(LDS + LS_BUF2 + grow * 144 + kb);
            short8 bv0 = *(const short8*)(LDS + LS_W2T + gc0 * 144 + kb);
            short8 bv1 = *(const short8*)(LDS + LS_W2T + gc1 * 144 + kb);
            a0 = __builtin_amdgcn_mfma_f32_32x32x16_bf16(av, bv0, a0, 0, 0, 0);
            a1 = __builtin_amdgcn_mfma_f32_32x32x16_bf16(av, bv1, a1, 0, 0, 0);
        }
#pragma unroll
        for (int g = 0; g < 4; ++g) {
            int j0 = tr * 32 + 8 * g + 4 * hi32;
            if (j0 < 200) {
                float4 dv4 = *(const float4*)(LDS + LS_DINV + j0 * 4);
                uint2 u0, u1;
                u0.x = bf16r(dv4.x * a0[4*g+0]) | (bf16r(dv4.y * a0[4*g+1]) << 16);
                u0.y = bf16r(dv4.z * a0[4*g+2]) | (bf16r(dv4.w * a0[4*g+3]) << 16);
                u1.x = bf16r(dv4.x * a1[4*g+0]) | (bf16r(dv4.y * a1[4*g+1]) << 16);
                u1.y = bf16r(dv4.z * a1[4*g+2]) | (bf16r(dv4.w * a1[4*g+3]) << 16);
                *(uint2*)(LDS + LS_YT + gc0 * 464 + j0 * 2) = u0;
                *(uint2*)(LDS + LS_YT + gc1 * 464 + j0 * 2) = u1;
            }
        }
    }
    __syncthreads();

    // ---- G4: z2 = A @ y2; out = relu(dinv_i*(z2 + y2_i) + b2) ----
    if (wid < 7) {
        f32x16 a0 = {}, a1 = {};
#pragma unroll
        for (int ch = 0; ch < 13; ++ch) {
            int kb = ch * 32 + hi32 * 16;
            short8 av = *(const short8*)(LDS + grow * 464 + kb);
            short8 bv0 = *(const short8*)(LDS + LS_YT + gc0 * 464 + kb);
            short8 bv1 = *(const short8*)(LDS + LS_YT + gc1 * 464 + kb);
            a0 = __builtin_amdgcn_mfma_f32_32x32x16_bf16(av, bv0, a0, 0, 0, 0);
            a1 = __builtin_amdgcn_mfma_f32_32x32x16_bf16(av, bv1, a1, 0, 0, 0);
        }
        float bias0 = *(const float*)(LDS + LS_B2 + gc0 * 4);
        float bias1 = *(const float*)(LDS + LS_B2 + gc1 * 4);
#pragma unroll
        for (int g = 0; g < 4; ++g) {
            int i0 = tr * 32 + 8 * g + 4 * hi32;
            if (i0 < 200) {
                float4 dv4 = *(const float4*)(LDS + LS_DINV + i0 * 4);
                uint2 yv0 = *(const uint2*)(LDS + LS_YT + gc0 * 464 + i0 * 2);
                uint2 yv1 = *(const uint2*)(LDS + LS_YT + gc1 * 464 + i0 * 2);
                float* ob = out + ((size_t)b * N + i0) * H;
#pragma unroll
                for (int q = 0; q < 4; ++q) {
                    float dq = (q == 0) ? dv4.x : (q == 1) ? dv4.y : (q == 2) ? dv4.z : dv4.w;
                    unsigned yw0 = (q < 2) ? yv0.x : yv0.y;
                    unsigned yw1 = (q < 2) ? yv1.x : yv1.y;
                    float y0 = bf2f((unsigned short)((q & 1) ? (yw0 >> 16) : (yw0 & 0xffff)));
                    float y1 = bf2f((unsigned short)((q & 1) ? (yw1 >> 16) : (yw1 & 0xffff)));
                    ob[q * H + gc0] = fmaxf(dq * (a0[4*g+q] + y0) + bias0, 0.f);
                    ob[q * H + gc1] = fmaxf(dq * (a1[4*g+q] + y1) + bias1, 0.f);
                }
            }
        }
    }
}

extern "C" void kernel_launch(void* const* d_in, const int* in_sizes, int n_in,
                              void* d_out, int out_size, void* d_ws, size_t ws_size,
                              hipStream_t stream) {
    const float* data = (const float*)d_in[0];
    const float* W1   = (const float*)d_in[1];
    const float* b1   = (const float*)d_in[2];
    const float* W2   = (const float*)d_in[3];
    const float* b2   = (const float*)d_in[4];
    float* out = (float*)d_out;

    hipLaunchKernelGGL(k_fused, dim3(B), dim3(NT), 0, stream, data, W1, b1, W2, b2, out);
}